// Round 12
// baseline (5159.787 us; speedup 1.0000x reference)
//
#include <hip/hip_runtime.h>
#include <hip/hip_bf16.h>

#define N_NODES 100000
#define N_EDGES 3200000
#define IN_F 128
#define OUT_F 64
#define HEADS 8
#define ALPHA 0.2f

#define BSHIFT 7
#define NBUCK 782           // ceil(100000 / 128)
#define CHUNK 16384         // edges per partition block
#define NPBLK 196           // ceil(N_EDGES / CHUNK)

typedef __bf16 bf16x8 __attribute__((ext_vector_type(8)));
typedef float f32x4 __attribute__((ext_vector_type(4)));
typedef __attribute__((ext_vector_type(8))) unsigned short ushort8;

static __device__ __forceinline__ unsigned short f2b(float f) {
    __hip_bfloat16 h = __float2bfloat16(f);
    return __builtin_bit_cast(unsigned short, h);
}

static __device__ __forceinline__ void gll16(const void* g, void* l) {
    __builtin_amdgcn_global_load_lds(
        (const __attribute__((address_space(1))) void*)g,
        (__attribute__((address_space(3))) void*)l, 16, 0, 0);
}

// ------- merged prep: Wt transpose (blocks 0-255), u/v (block 256),
//         bhist zero (block 257) ------------------------------------------
__global__ __launch_bounds__(256) void k_prep(const float* __restrict__ W,
                                              const float* __restrict__ a,
                                              unsigned short* __restrict__ Wt,
                                              float* __restrict__ u,
                                              float* __restrict__ v,
                                              int* __restrict__ bhist) {
    int b = blockIdx.x, t = threadIdx.x;
    if (b < 256) {
        int idx = b * 256 + t;          // c*128 + k
        int k = idx & 127;
        int c = idx >> 7;
        int h = c >> 6;
        int f = c & 63;
        Wt[idx] = f2b(W[h * IN_F * OUT_F + k * OUT_F + f]);
    } else if (b == 256) {
#pragma unroll
        for (int j = 0; j < 4; ++j) {
            int t2 = t + j * 256;       // 0..1023 = h*128+k
            int h = t2 >> 7, k = t2 & 127;
            const float* Wrow = W + h * IN_F * OUT_F + k * OUT_F;
            const float* ah = a + h * 2 * OUT_F;
            float su = 0.f, sv = 0.f;
            for (int f = 0; f < OUT_F; ++f) {
                float wv = Wrow[f];
                su += wv * ah[f];
                sv += wv * ah[OUT_F + f];
            }
            u[t2] = su;
            v[t2] = sv;
        }
    } else {
        for (int i = t; i < NBUCK; i += 256) bhist[i] = 0;
    }
}

// ------- fused: x -> bf16 copy, and logits asrc/atgt via u,v dots ----------
__global__ __launch_bounds__(256) void k_xadot(const float* __restrict__ x,
                                               const float* __restrict__ u,
                                               const float* __restrict__ v,
                                               unsigned short* __restrict__ xb,
                                               float* __restrict__ asrc,
                                               float* __restrict__ atgt) {
    int node = (blockIdx.x * 256 + threadIdx.x) >> 6;
    int lane = threadIdx.x & 63;
    if (node >= N_NODES) return;
    float2 xv = *reinterpret_cast<const float2*>(x + (size_t)node * 128 + 2 * lane);
    ushort2 pv = make_ushort2(f2b(xv.x), f2b(xv.y));
    *reinterpret_cast<ushort2*>(xb + (size_t)node * 128 + 2 * lane) = pv;
    for (int h = 0; h < 8; ++h) {
        float2 uu = *reinterpret_cast<const float2*>(u + h * 128 + 2 * lane);
        float2 vv = *reinterpret_cast<const float2*>(v + h * 128 + 2 * lane);
        float s1 = xv.x * uu.x + xv.y * uu.y;
        float s2 = xv.x * vv.x + xv.y * vv.y;
        for (int d = 1; d < 64; d <<= 1) {
            s1 += __shfl_xor(s1, d);
            s2 += __shfl_xor(s2, d);
        }
        if (lane == 0) {
            asrc[node * 8 + h] = s1;
            atgt[node * 8 + h] = s2;
        }
    }
}

// ---------------- pass 0: global bucket histogram (LDS-privatized) --------
__global__ __launch_bounds__(256) void k_bcount(const int* __restrict__ src,
                                                int* __restrict__ bhist) {
    __shared__ int h[NBUCK];
    for (int i = threadIdx.x; i < NBUCK; i += 256) h[i] = 0;
    __syncthreads();
    int i0 = blockIdx.x * CHUNK;
    int iend = i0 + CHUNK;
    if (iend > N_EDGES) iend = N_EDGES;
    for (int i = i0 + threadIdx.x; i < iend; i += 256)
        atomicAdd(&h[src[i] >> BSHIFT], 1);
    __syncthreads();
    for (int i = threadIdx.x; i < NBUCK; i += 256)
        if (h[i]) atomicAdd(&bhist[i], h[i]);
}

// ---------------- bucket scan (1 block); also init cursors ----------------
__global__ __launch_bounds__(1024) void k_bscan(const int* __restrict__ bhist,
                                                int* __restrict__ bstart,
                                                int* __restrict__ bcursor,
                                                int* __restrict__ rowptr) {
    __shared__ int s[1024];
    int t = threadIdx.x;
    int v = (t < NBUCK) ? bhist[t] : 0;
    s[t] = v;
    __syncthreads();
    for (int d = 1; d < 1024; d <<= 1) {
        int add = (t >= d) ? s[t - d] : 0;
        __syncthreads();
        s[t] += add;
        __syncthreads();
    }
    if (t < NBUCK) {
        int st = s[t] - v;
        bstart[t] = st;
        bcursor[t] = st;
    }
    if (t == 0) {
        bstart[NBUCK] = N_EDGES;
        rowptr[N_NODES] = N_EDGES;
    }
}

// ---------------- pass 1: partition edges into bucket regions -------------
// packed pair: (src&127) << 17 | tgt   (tgt < 2^17)
__global__ __launch_bounds__(256) void k_bscatter(const int* __restrict__ src,
                                                  const int* __restrict__ tgt,
                                                  int* __restrict__ bcursor,
                                                  unsigned int* __restrict__ pairs) {
    __shared__ int h[NBUCK];
    __shared__ int rsv[NBUCK];
    for (int i = threadIdx.x; i < NBUCK; i += 256) h[i] = 0;
    __syncthreads();
    int i0 = blockIdx.x * CHUNK;
    int iend = i0 + CHUNK;
    if (iend > N_EDGES) iend = N_EDGES;
    for (int i = i0 + threadIdx.x; i < iend; i += 256)
        atomicAdd(&h[src[i] >> BSHIFT], 1);
    __syncthreads();
    for (int i = threadIdx.x; i < NBUCK; i += 256) {
        int c = h[i];
        rsv[i] = c ? atomicAdd(&bcursor[i], c) : 0;
        h[i] = 0;
    }
    __syncthreads();
    for (int i = i0 + threadIdx.x; i < iend; i += 256) {
        int s = src[i];
        int b = s >> BSHIFT;
        int p = rsv[b] + atomicAdd(&h[b], 1);
        pairs[p] = ((unsigned)(s & 127) << 17) | (unsigned)tgt[i];
    }
}

// ---------------- pass 2: in-bucket counting sort -> stgt + rowptr --------
__global__ __launch_bounds__(256) void k_bsort(const unsigned int* __restrict__ pairs,
                                               const int* __restrict__ bstart,
                                               int* __restrict__ rowptr,
                                               int* __restrict__ stgt) {
    __shared__ int h[128];
    __shared__ int s[128];
    int b = blockIdx.x;
    int p0 = bstart[b], p1 = bstart[b + 1];
    int n0 = b << BSHIFT;
    int t = threadIdx.x;
    if (t < 128) h[t] = 0;
    __syncthreads();
    for (int i = p0 + t; i < p1; i += 256)
        atomicAdd(&h[pairs[i] >> 17], 1);
    __syncthreads();
    int v = (t < 128) ? h[t] : 0;
    if (t < 128) s[t] = v;
    __syncthreads();
    for (int d = 1; d < 128; d <<= 1) {
        int add = (t >= d && t < 128) ? s[t - d] : 0;
        __syncthreads();
        if (t < 128) s[t] += add;
        __syncthreads();
    }
    if (t < 128) {
        int pos = p0 + s[t] - v;
        int node = n0 + t;
        if (node < N_NODES) rowptr[node] = pos;
        h[t] = pos;
    }
    __syncthreads();
    for (int i = p0 + t; i < p1; i += 256) {
        unsigned int pr = pairs[i];
        int pos = atomicAdd(&h[pr >> 17], 1);
        stgt[pos] = (int)(pr & 0x1FFFF);
    }
}

// ------- k_agg8: one node/wave, quarter-wave = distinct edge --------------
// Chunk = 16 edges. Per-wave LDS (x2 dbuf, 5120B):
//   [0, 1024):   atgt rows 32B/edge (staged; overwritten by fp32 w[e][h])
//   [1024,5120): X[e][seg] 16 x 256B bf16 rows (linear)
// Staging: 5x global_load_lds (16B/lane, zero duplication).
// Weight phase: lane (e=lane&15, hp=lane>>4) -> 2 exps, in-place write,
//   per-lane den for heads (2hp, 2hp+1).
// Compute: 4 iters; lane (seg=lane&15, el2=lane>>4) handles edge it*4+el2:
//   1 ds_read_b128 X + 2 broadcast ds_read_b128 W + 8 unpack +
//   32 v_pk_fma_f32 (all 8 heads).
// End: acc reduce over el2 (xor 16,32); den reduce over e (xor 1,2,4,8);
//   lane (seg,q) writes heads 2q,2q+1 via STATIC-index cndmask select
//   (rule #20: runtime-indexed acc would demote the array to scratch).
__global__ __launch_bounds__(256) void k_agg8(const int* __restrict__ rowptr,
                                              const int* __restrict__ stgt,
                                              const float* __restrict__ asrc,
                                              const float* __restrict__ atgt,
                                              const unsigned short* __restrict__ xb,
                                              unsigned short* __restrict__ aggout) {
    __shared__ char lds[4 * 2 * 5120];
    const int tid = threadIdx.x;
    const int wid = tid >> 6, lane = tid & 63;
    const int node = blockIdx.x * 4 + wid;
    if (node >= N_NODES) return;
    const int seg = lane & 15;           // 16B x-segment / weight-phase edge
    const int q = lane >> 4;             // el2 in compute, hp in weight phase
    const int base = rowptr[node], end = rowptr[node + 1];
    const int deg = end - base;
    const float2 asr = *reinterpret_cast<const float2*>(asrc + (size_t)node * 8 + q * 2);
    char* wbase = lds + wid * 10240;

    float2 acc[8][4] = {};               // [feat-in-seg][head-pair]
    float den0 = 0.f, den1 = 0.f;        // heads 2q, 2q+1 (partial over e-slots)

    const int nch = (deg + 15) >> 4;

    auto eidx = [&](int c) {
        int i = base + c * 16 + seg;
        if (i >= end) i = end - 1;
        return i;
    };
    auto stage = [&](char* buf, int t16) {
        int ta = __shfl(t16, (lane & 31) >> 1);
        gll16(atgt + (size_t)ta * 8 + (lane & 1) * 4, buf);
#pragma unroll
        for (int p = 0; p < 4; ++p) {
            int te = __shfl(t16, p * 4 + q);
            gll16(xb + (size_t)te * 128 + seg * 8, buf + 1024 + p * 1024);
        }
    };

#define PK(ACC, X2, W2) \
    asm("v_pk_fma_f32 %0, %1, %2, %0" : "+v"(ACC) : "v"(X2), "v"(W2));

    if (nch > 0) {
        int t16 = stgt[eidx(0)];
        stage(wbase, t16);
        if (nch > 1) t16 = stgt[eidx(1)];
        asm volatile("s_waitcnt vmcnt(0)" ::: "memory");
        int cur = 0;
        for (int c = 0; c < nch; ++c) {
            if (c + 1 < nch) {
                stage(wbase + (cur ^ 1) * 5120, t16);
                if (c + 2 < nch) t16 = stgt[eidx(c + 2)];
            }
            char* buf = wbase + cur * 5120;
            int cnt = deg - c * 16;      // valid edges this chunk (<=16 used)
            // ---- weight phase: lane (e=seg, hp=q), in-place over [0,1024)
            {
                float2 at2 = *reinterpret_cast<const float2*>(buf + seg * 32 + q * 8);
                float z0 = asr.x + at2.x, z1 = asr.y + at2.y;
                float e0 = (z0 > 0.f) ? -z0 : -(ALPHA * z0);
                float e1 = (z1 > 0.f) ? -z1 : -(ALPHA * z1);
                bool ok = seg < cnt;
                float w0 = ok ? __expf(e0) : 0.f;
                float w1 = ok ? __expf(e1) : 0.f;
                den0 += w0;
                den1 += w1;
                float2 wout = {w0, w1};
                *reinterpret_cast<float2*>(buf + seg * 32 + q * 8) = wout;
            }
            asm volatile("s_waitcnt lgkmcnt(0)" ::: "memory");
            __builtin_amdgcn_sched_barrier(0);
            // ---- compute: 4 iters x 4 edges (one per quarter)
            const char* Xb = buf + 1024;
#pragma unroll
            for (int it = 0; it < 4; ++it) {
                int e = it * 4 + q;
                uint4 xu = *reinterpret_cast<const uint4*>(Xb + e * 256 + seg * 16);
                float4 wA = *reinterpret_cast<const float4*>(buf + e * 32);
                float4 wB = *reinterpret_cast<const float4*>(buf + e * 32 + 16);
                float2 w01 = {wA.x, wA.y}, w23 = {wA.z, wA.w};
                float2 w45 = {wB.x, wB.y}, w67 = {wB.z, wB.w};
#pragma unroll
                for (int i = 0; i < 4; ++i) {
                    unsigned int uu = (&xu.x)[i];
                    float xlo = __builtin_bit_cast(float, uu << 16);
                    float xhi = __builtin_bit_cast(float, uu & 0xFFFF0000u);
                    float2 xl2 = {xlo, xlo};
                    float2 xh2 = {xhi, xhi};
                    PK(acc[2 * i][0], xl2, w01)
                    PK(acc[2 * i][1], xl2, w23)
                    PK(acc[2 * i][2], xl2, w45)
                    PK(acc[2 * i][3], xl2, w67)
                    PK(acc[2 * i + 1][0], xh2, w01)
                    PK(acc[2 * i + 1][1], xh2, w23)
                    PK(acc[2 * i + 1][2], xh2, w45)
                    PK(acc[2 * i + 1][3], xh2, w67)
                }
            }
            asm volatile("s_waitcnt vmcnt(0)" ::: "memory");
            cur ^= 1;
        }
    }
#undef PK

    // ---- reduce acc over the 4 el2 groups (quarters); static indices only
#pragma unroll
    for (int f = 0; f < 8; ++f)
#pragma unroll
        for (int p = 0; p < 4; ++p) {
            acc[f][p].x += __shfl_xor(acc[f][p].x, 16);
            acc[f][p].y += __shfl_xor(acc[f][p].y, 16);
            acc[f][p].x += __shfl_xor(acc[f][p].x, 32);
            acc[f][p].y += __shfl_xor(acc[f][p].y, 32);
        }
    // ---- reduce den over the 16 e-slots (bits 0..3); result valid per hp=q
    for (int d = 1; d <= 8; d <<= 1) {
        den0 += __shfl_xor(den0, d);
        den1 += __shfl_xor(den1, d);
    }
    float inv0 = 1.f / (den0 + 1e-10f);
    float inv1 = 1.f / (den1 + 1e-10f);

    // ---- lane (seg,q) writes heads 2q, 2q+1: STATIC-index cndmask select
    const bool qb0 = (q & 1) != 0, qb1 = (q & 2) != 0;
    ushort8 o0, o1;
#pragma unroll
    for (int f = 0; f < 8; ++f) {
        float2 va, vb, vs;
        va.x = qb0 ? acc[f][1].x : acc[f][0].x;
        va.y = qb0 ? acc[f][1].y : acc[f][0].y;
        vb.x = qb0 ? acc[f][3].x : acc[f][2].x;
        vb.y = qb0 ? acc[f][3].y : acc[f][2].y;
        vs.x = qb1 ? vb.x : va.x;
        vs.y = qb1 ? vb.y : va.y;
        o0[f] = f2b(vs.x * inv0);
        o1[f] = f2b(vs.y * inv1);
    }
    unsigned short* op = aggout + (size_t)node * 1024 + (2 * q) * 128 + seg * 8;
    *reinterpret_cast<ushort8*>(op) = o0;
    *reinterpret_cast<ushort8*>(op + 128) = o1;
}

// ------- final per-head GEMM: out[r][h*64+f] = agg[r][h][:] @ W[h][:][f] ---
#define LDK2 136
__global__ __launch_bounds__(256) void k_gemm2(const unsigned short* __restrict__ agg,
                                               const unsigned short* __restrict__ Wt,
                                               float* __restrict__ out) {
    __shared__ unsigned short Al[64 * LDK2];
    __shared__ unsigned short Bl[64 * LDK2];
    const int tid = threadIdx.x;
    const int h = blockIdx.y;
    const int r0 = blockIdx.x * 64;
    for (int it = 0; it < 4; ++it) {
        int idx = tid + it * 256;
        int r = idx >> 4, k8 = (idx & 15) << 3;
        int gr = r0 + r;
        if (gr >= N_NODES) gr = N_NODES - 1;
        *reinterpret_cast<ushort8*>(&Al[r * LDK2 + k8]) =
            *reinterpret_cast<const ushort8*>(agg + (size_t)gr * 1024 + h * 128 + k8);
    }
    for (int it = 0; it < 4; ++it) {
        int idx = tid + it * 256;
        int f = idx >> 4, k8 = (idx & 15) << 3;
        *reinterpret_cast<ushort8*>(&Bl[f * LDK2 + k8]) =
            *reinterpret_cast<const ushort8*>(Wt + (size_t)(h * 64 + f) * 128 + k8);
    }
    __syncthreads();
    const int lane = tid & 63, w = tid >> 6;
    const int l15 = lane & 15, lq = lane >> 4;
    f32x4 acc[4] = {};
    for (int ks = 0; ks < 4; ++ks) {
        int koff = ks * 32 + lq * 8;
        bf16x8 af = *reinterpret_cast<const bf16x8*>(&Al[(w * 16 + l15) * LDK2 + koff]);
#pragma unroll
        for (int n = 0; n < 4; ++n) {
            bf16x8 bf_ = *reinterpret_cast<const bf16x8*>(&Bl[(n * 16 + l15) * LDK2 + koff]);
            acc[n] = __builtin_amdgcn_mfma_f32_16x16x32_bf16(af, bf_, acc[n], 0, 0, 0);
        }
    }
    for (int n = 0; n < 4; ++n) {
        int col = h * 64 + n * 16 + l15;
        int rbase = r0 + w * 16 + lq * 4;
#pragma unroll
        for (int r2 = 0; r2 < 4; ++r2) {
            int rr = rbase + r2;
            if (rr < N_NODES) out[(size_t)rr * 512 + col] = acc[n][r2];
        }
    }
}

extern "C" void kernel_launch(void* const* d_in, const int* in_sizes, int n_in,
                              void* d_out, int out_size, void* d_ws, size_t ws_size,
                              hipStream_t stream) {
    const float* x = (const float*)d_in[0];
    const int* edges = (const int*)d_in[1];
    const float* W = (const float*)d_in[2];
    const float* a = (const float*)d_in[3];
    float* out = (float*)d_out;
    const int* src = edges;
    const int* tgt = edges + N_EDGES;

    char* ws = (char*)d_ws;
    size_t off = 0;
    auto alloc = [&](size_t bytes) -> void* {
        void* p = (void*)(ws + off);
        off += (bytes + 255) & ~(size_t)255;
        return p;
    };
    unsigned short* Wt = (unsigned short*)alloc((size_t)HEADS * OUT_F * IN_F * 2);
    float* u = (float*)alloc(HEADS * IN_F * 4);
    float* v = (float*)alloc(HEADS * IN_F * 4);
    unsigned short* xb = (unsigned short*)alloc((size_t)N_NODES * IN_F * 2);  // 25.6 MB
    float* asrc = (float*)alloc((size_t)N_NODES * 8 * 4);
    float* atgt = (float*)alloc((size_t)N_NODES * 8 * 4);
    int* bhist = (int*)alloc((size_t)NBUCK * 4);
    int* bstart = (int*)alloc((size_t)(NBUCK + 1) * 4);
    int* bcursor = (int*)alloc((size_t)NBUCK * 4);
    int* rowptr = (int*)alloc((size_t)(N_NODES + 1) * 4);
    unsigned int* pairs = (unsigned int*)alloc((size_t)N_EDGES * 4);  // 12.8 MB
    int* stgt = (int*)alloc((size_t)N_EDGES * 4);                     // 12.8 MB
    (void)ws_size; (void)n_in; (void)in_sizes; (void)out_size;

    k_prep<<<258, 256, 0, stream>>>(W, a, Wt, u, v, bhist);
    k_xadot<<<25000, 256, 0, stream>>>(x, u, v, xb, asrc, atgt);
    k_bcount<<<NPBLK, 256, 0, stream>>>(src, bhist);
    k_bscan<<<1, 1024, 0, stream>>>(bhist, bstart, bcursor, rowptr);
    k_bscatter<<<NPBLK, 256, 0, stream>>>(src, tgt, bcursor, pairs);
    k_bsort<<<NBUCK, 256, 0, stream>>>(pairs, bstart, rowptr, stgt);
    k_agg8<<<25000, 256, 0, stream>>>(rowptr, stgt, asrc, atgt, xb,
                                      (unsigned short*)d_out);
    k_gemm2<<<dim3(1563, 8), 256, 0, stream>>>((const unsigned short*)d_out, Wt, out);
}

// Round 13
// 670.510 us; speedup vs baseline: 7.6953x; 7.6953x over previous
//
#include <hip/hip_runtime.h>
#include <hip/hip_bf16.h>

#define N_NODES 100000
#define N_EDGES 3200000
#define IN_F 128
#define OUT_F 64
#define HEADS 8
#define ALPHA 0.2f

#define BSHIFT 7
#define NBUCK 782           // ceil(100000 / 128)
#define CHUNK 16384         // edges per partition block
#define NPBLK 196           // ceil(N_EDGES / CHUNK)

typedef __bf16 bf16x8 __attribute__((ext_vector_type(8)));
typedef float f32x4 __attribute__((ext_vector_type(4)));
typedef __attribute__((ext_vector_type(8))) unsigned short ushort8;

static __device__ __forceinline__ unsigned short f2b(float f) {
    __hip_bfloat16 h = __float2bfloat16(f);
    return __builtin_bit_cast(unsigned short, h);
}

static __device__ __forceinline__ void gll16(const void* g, void* l) {
    __builtin_amdgcn_global_load_lds(
        (const __attribute__((address_space(1))) void*)g,
        (__attribute__((address_space(3))) void*)l, 16, 0, 0);
}

// ------- merged prep: Wt transpose (blocks 0-255), u/v (block 256),
//         bhist zero (block 257) ------------------------------------------
__global__ __launch_bounds__(256) void k_prep(const float* __restrict__ W,
                                              const float* __restrict__ a,
                                              unsigned short* __restrict__ Wt,
                                              float* __restrict__ u,
                                              float* __restrict__ v,
                                              int* __restrict__ bhist) {
    int b = blockIdx.x, t = threadIdx.x;
    if (b < 256) {
        int idx = b * 256 + t;          // c*128 + k
        int k = idx & 127;
        int c = idx >> 7;
        int h = c >> 6;
        int f = c & 63;
        Wt[idx] = f2b(W[h * IN_F * OUT_F + k * OUT_F + f]);
    } else if (b == 256) {
#pragma unroll
        for (int j = 0; j < 4; ++j) {
            int t2 = t + j * 256;       // 0..1023 = h*128+k
            int h = t2 >> 7, k = t2 & 127;
            const float* Wrow = W + h * IN_F * OUT_F + k * OUT_F;
            const float* ah = a + h * 2 * OUT_F;
            float su = 0.f, sv = 0.f;
            for (int f = 0; f < OUT_F; ++f) {
                float wv = Wrow[f];
                su += wv * ah[f];
                sv += wv * ah[OUT_F + f];
            }
            u[t2] = su;
            v[t2] = sv;
        }
    } else {
        for (int i = t; i < NBUCK; i += 256) bhist[i] = 0;
    }
}

// ------- fused: x -> bf16 copy, and logits asrc/atgt via u,v dots ----------
__global__ __launch_bounds__(256) void k_xadot(const float* __restrict__ x,
                                               const float* __restrict__ u,
                                               const float* __restrict__ v,
                                               unsigned short* __restrict__ xb,
                                               float* __restrict__ asrc,
                                               float* __restrict__ atgt) {
    int node = (blockIdx.x * 256 + threadIdx.x) >> 6;
    int lane = threadIdx.x & 63;
    if (node >= N_NODES) return;
    float2 xv = *reinterpret_cast<const float2*>(x + (size_t)node * 128 + 2 * lane);
    ushort2 pv = make_ushort2(f2b(xv.x), f2b(xv.y));
    *reinterpret_cast<ushort2*>(xb + (size_t)node * 128 + 2 * lane) = pv;
    for (int h = 0; h < 8; ++h) {
        float2 uu = *reinterpret_cast<const float2*>(u + h * 128 + 2 * lane);
        float2 vv = *reinterpret_cast<const float2*>(v + h * 128 + 2 * lane);
        float s1 = xv.x * uu.x + xv.y * uu.y;
        float s2 = xv.x * vv.x + xv.y * vv.y;
        for (int d = 1; d < 64; d <<= 1) {
            s1 += __shfl_xor(s1, d);
            s2 += __shfl_xor(s2, d);
        }
        if (lane == 0) {
            asrc[node * 8 + h] = s1;
            atgt[node * 8 + h] = s2;
        }
    }
}

// ---------------- pass 0: global bucket histogram (LDS-privatized) --------
__global__ __launch_bounds__(256) void k_bcount(const int* __restrict__ src,
                                                int* __restrict__ bhist) {
    __shared__ int h[NBUCK];
    for (int i = threadIdx.x; i < NBUCK; i += 256) h[i] = 0;
    __syncthreads();
    int i0 = blockIdx.x * CHUNK;
    int iend = i0 + CHUNK;
    if (iend > N_EDGES) iend = N_EDGES;
    for (int i = i0 + threadIdx.x; i < iend; i += 256)
        atomicAdd(&h[src[i] >> BSHIFT], 1);
    __syncthreads();
    for (int i = threadIdx.x; i < NBUCK; i += 256)
        if (h[i]) atomicAdd(&bhist[i], h[i]);
}

// ---------------- bucket scan (1 block); also init cursors ----------------
__global__ __launch_bounds__(1024) void k_bscan(const int* __restrict__ bhist,
                                                int* __restrict__ bstart,
                                                int* __restrict__ bcursor,
                                                int* __restrict__ rowptr) {
    __shared__ int s[1024];
    int t = threadIdx.x;
    int v = (t < NBUCK) ? bhist[t] : 0;
    s[t] = v;
    __syncthreads();
    for (int d = 1; d < 1024; d <<= 1) {
        int add = (t >= d) ? s[t - d] : 0;
        __syncthreads();
        s[t] += add;
        __syncthreads();
    }
    if (t < NBUCK) {
        int st = s[t] - v;
        bstart[t] = st;
        bcursor[t] = st;
    }
    if (t == 0) {
        bstart[NBUCK] = N_EDGES;
        rowptr[N_NODES] = N_EDGES;
    }
}

// ---------------- pass 1: partition edges into bucket regions -------------
// packed pair: (src&127) << 17 | tgt   (tgt < 2^17)
__global__ __launch_bounds__(256) void k_bscatter(const int* __restrict__ src,
                                                  const int* __restrict__ tgt,
                                                  int* __restrict__ bcursor,
                                                  unsigned int* __restrict__ pairs) {
    __shared__ int h[NBUCK];
    __shared__ int rsv[NBUCK];
    for (int i = threadIdx.x; i < NBUCK; i += 256) h[i] = 0;
    __syncthreads();
    int i0 = blockIdx.x * CHUNK;
    int iend = i0 + CHUNK;
    if (iend > N_EDGES) iend = N_EDGES;
    for (int i = i0 + threadIdx.x; i < iend; i += 256)
        atomicAdd(&h[src[i] >> BSHIFT], 1);
    __syncthreads();
    for (int i = threadIdx.x; i < NBUCK; i += 256) {
        int c = h[i];
        rsv[i] = c ? atomicAdd(&bcursor[i], c) : 0;
        h[i] = 0;
    }
    __syncthreads();
    for (int i = i0 + threadIdx.x; i < iend; i += 256) {
        int s = src[i];
        int b = s >> BSHIFT;
        int p = rsv[b] + atomicAdd(&h[b], 1);
        pairs[p] = ((unsigned)(s & 127) << 17) | (unsigned)tgt[i];
    }
}

// ---------------- pass 2: in-bucket counting sort -> stgt + rowptr --------
__global__ __launch_bounds__(256) void k_bsort(const unsigned int* __restrict__ pairs,
                                               const int* __restrict__ bstart,
                                               int* __restrict__ rowptr,
                                               int* __restrict__ stgt) {
    __shared__ int h[128];
    __shared__ int s[128];
    int b = blockIdx.x;
    int p0 = bstart[b], p1 = bstart[b + 1];
    int n0 = b << BSHIFT;
    int t = threadIdx.x;
    if (t < 128) h[t] = 0;
    __syncthreads();
    for (int i = p0 + t; i < p1; i += 256)
        atomicAdd(&h[pairs[i] >> 17], 1);
    __syncthreads();
    int v = (t < 128) ? h[t] : 0;
    if (t < 128) s[t] = v;
    __syncthreads();
    for (int d = 1; d < 128; d <<= 1) {
        int add = (t >= d && t < 128) ? s[t - d] : 0;
        __syncthreads();
        if (t < 128) s[t] += add;
        __syncthreads();
    }
    if (t < 128) {
        int pos = p0 + s[t] - v;
        int node = n0 + t;
        if (node < N_NODES) rowptr[node] = pos;
        h[t] = pos;
    }
    __syncthreads();
    for (int i = p0 + t; i < p1; i += 256) {
        unsigned int pr = pairs[i];
        int pos = atomicAdd(&h[pr >> 17], 1);
        stgt[pos] = (int)(pr & 0x1FFFF);
    }
}

// ------- k_agg9: agg8 algorithm with 32 NAMED accumulators ---------------
// Rule #20 (named-variable form): acc array was demoted to scratch even
// with static selects (clang re-canonicalizes select chains into dynamic
// GEPs); 32 named float2 locals make demotion impossible.
// Layout identical to agg8: chunk=16 edges, dbuf 5120B/wave,
//   [0,1024) atgt->weights in place, [1024,5120) X rows.
// Lane (seg=lane&15, q=lane>>4). aP_F = acc for head-pair P, feat F.
__global__ __launch_bounds__(256) void k_agg9(const int* __restrict__ rowptr,
                                              const int* __restrict__ stgt,
                                              const float* __restrict__ asrc,
                                              const float* __restrict__ atgt,
                                              const unsigned short* __restrict__ xb,
                                              unsigned short* __restrict__ aggout) {
    __shared__ char lds[4 * 2 * 5120];
    const int tid = threadIdx.x;
    const int wid = tid >> 6, lane = tid & 63;
    const int node = blockIdx.x * 4 + wid;
    if (node >= N_NODES) return;
    const int seg = lane & 15;
    const int q = lane >> 4;
    const int base = rowptr[node], end = rowptr[node + 1];
    const int deg = end - base;
    const float2 asr = *reinterpret_cast<const float2*>(asrc + (size_t)node * 8 + q * 2);
    char* wbase = lds + wid * 10240;

#define DECLF(F) float2 a0_##F = {0.f, 0.f}, a1_##F = {0.f, 0.f}, \
                        a2_##F = {0.f, 0.f}, a3_##F = {0.f, 0.f};
    DECLF(0) DECLF(1) DECLF(2) DECLF(3) DECLF(4) DECLF(5) DECLF(6) DECLF(7)
#undef DECLF
    float den0 = 0.f, den1 = 0.f;

    const int nch = (deg + 15) >> 4;

    auto eidx = [&](int c) {
        int i = base + c * 16 + seg;
        if (i >= end) i = end - 1;
        return i;
    };
    auto stage = [&](char* buf, int t16) {
        int ta = __shfl(t16, (lane & 31) >> 1);
        gll16(atgt + (size_t)ta * 8 + (lane & 1) * 4, buf);
#pragma unroll
        for (int p = 0; p < 4; ++p) {
            int te = __shfl(t16, p * 4 + q);
            gll16(xb + (size_t)te * 128 + seg * 8, buf + 1024 + p * 1024);
        }
    };

#define PK(ACC, X2, W2) \
    asm("v_pk_fma_f32 %0, %1, %2, %0" : "+v"(ACC) : "v"(X2), "v"(W2));
#define ISTEP(UU, F0, F1) { \
        unsigned int uu_ = (UU); \
        float xlo_ = __builtin_bit_cast(float, uu_ << 16); \
        float xhi_ = __builtin_bit_cast(float, uu_ & 0xFFFF0000u); \
        float2 xl2_ = {xlo_, xlo_}; \
        float2 xh2_ = {xhi_, xhi_}; \
        PK(a0_##F0, xl2_, w01) PK(a1_##F0, xl2_, w23) \
        PK(a2_##F0, xl2_, w45) PK(a3_##F0, xl2_, w67) \
        PK(a0_##F1, xh2_, w01) PK(a1_##F1, xh2_, w23) \
        PK(a2_##F1, xh2_, w45) PK(a3_##F1, xh2_, w67) \
    }

    if (nch > 0) {
        int t16 = stgt[eidx(0)];
        stage(wbase, t16);
        if (nch > 1) t16 = stgt[eidx(1)];
        asm volatile("s_waitcnt vmcnt(0)" ::: "memory");
        int cur = 0;
        for (int c = 0; c < nch; ++c) {
            if (c + 1 < nch) {
                stage(wbase + (cur ^ 1) * 5120, t16);
                if (c + 2 < nch) t16 = stgt[eidx(c + 2)];
            }
            char* buf = wbase + cur * 5120;
            int cnt = deg - c * 16;
            // ---- weight phase: lane (e=seg, hp=q), in-place over [0,1024)
            {
                float2 at2 = *reinterpret_cast<const float2*>(buf + seg * 32 + q * 8);
                float z0 = asr.x + at2.x, z1 = asr.y + at2.y;
                float e0 = (z0 > 0.f) ? -z0 : -(ALPHA * z0);
                float e1 = (z1 > 0.f) ? -z1 : -(ALPHA * z1);
                bool ok = seg < cnt;
                float w0 = ok ? __expf(e0) : 0.f;
                float w1 = ok ? __expf(e1) : 0.f;
                den0 += w0;
                den1 += w1;
                float2 wout = {w0, w1};
                *reinterpret_cast<float2*>(buf + seg * 32 + q * 8) = wout;
            }
            asm volatile("s_waitcnt lgkmcnt(0)" ::: "memory");
            __builtin_amdgcn_sched_barrier(0);
            // ---- compute: 4 iters x 4 edges (one per quarter)
            const char* Xb = buf + 1024;
#pragma unroll
            for (int it = 0; it < 4; ++it) {
                int e = it * 4 + q;
                uint4 xu = *reinterpret_cast<const uint4*>(Xb + e * 256 + seg * 16);
                float4 wA = *reinterpret_cast<const float4*>(buf + e * 32);
                float4 wB = *reinterpret_cast<const float4*>(buf + e * 32 + 16);
                float2 w01 = {wA.x, wA.y}, w23 = {wA.z, wA.w};
                float2 w45 = {wB.x, wB.y}, w67 = {wB.z, wB.w};
                ISTEP(xu.x, 0, 1)
                ISTEP(xu.y, 2, 3)
                ISTEP(xu.z, 4, 5)
                ISTEP(xu.w, 6, 7)
            }
            asm volatile("s_waitcnt vmcnt(0)" ::: "memory");
            cur ^= 1;
        }
    }
#undef ISTEP
#undef PK

    // ---- reduce acc over the 4 quarters (named vars, fully static)
#define RED1(V) { V.x += __shfl_xor(V.x, 16); V.y += __shfl_xor(V.y, 16); \
                  V.x += __shfl_xor(V.x, 32); V.y += __shfl_xor(V.y, 32); }
#define REDF(F) RED1(a0_##F) RED1(a1_##F) RED1(a2_##F) RED1(a3_##F)
    REDF(0) REDF(1) REDF(2) REDF(3) REDF(4) REDF(5) REDF(6) REDF(7)
#undef REDF
#undef RED1
    // ---- reduce den over the 16 e-slots; result valid per hp=q
    for (int d = 1; d <= 8; d <<= 1) {
        den0 += __shfl_xor(den0, d);
        den1 += __shfl_xor(den1, d);
    }
    float inv0 = 1.f / (den0 + 1e-10f);
    float inv1 = 1.f / (den1 + 1e-10f);

    // ---- lane (seg,q) writes heads 2q, 2q+1 (named-var selects)
    const bool qb0 = (q & 1) != 0, qb1 = (q & 2) != 0;
    ushort8 o0, o1;
#define EPI(F) { \
        float vax = qb0 ? a1_##F.x : a0_##F.x; \
        float vay = qb0 ? a1_##F.y : a0_##F.y; \
        float vbx = qb0 ? a3_##F.x : a2_##F.x; \
        float vby = qb0 ? a3_##F.y : a2_##F.y; \
        float vsx = qb1 ? vbx : vax; \
        float vsy = qb1 ? vby : vay; \
        o0[F] = f2b(vsx * inv0); \
        o1[F] = f2b(vsy * inv1); }
    EPI(0) EPI(1) EPI(2) EPI(3) EPI(4) EPI(5) EPI(6) EPI(7)
#undef EPI
    unsigned short* op = aggout + (size_t)node * 1024 + (2 * q) * 128 + seg * 8;
    *reinterpret_cast<ushort8*>(op) = o0;
    *reinterpret_cast<ushort8*>(op + 128) = o1;
}

// ------- final per-head GEMM: out[r][h*64+f] = agg[r][h][:] @ W[h][:][f] ---
#define LDK2 136
__global__ __launch_bounds__(256) void k_gemm2(const unsigned short* __restrict__ agg,
                                               const unsigned short* __restrict__ Wt,
                                               float* __restrict__ out) {
    __shared__ unsigned short Al[64 * LDK2];
    __shared__ unsigned short Bl[64 * LDK2];
    const int tid = threadIdx.x;
    const int h = blockIdx.y;
    const int r0 = blockIdx.x * 64;
    for (int it = 0; it < 4; ++it) {
        int idx = tid + it * 256;
        int r = idx >> 4, k8 = (idx & 15) << 3;
        int gr = r0 + r;
        if (gr >= N_NODES) gr = N_NODES - 1;
        *reinterpret_cast<ushort8*>(&Al[r * LDK2 + k8]) =
            *reinterpret_cast<const ushort8*>(agg + (size_t)gr * 1024 + h * 128 + k8);
    }
    for (int it = 0; it < 4; ++it) {
        int idx = tid + it * 256;
        int f = idx >> 4, k8 = (idx & 15) << 3;
        *reinterpret_cast<ushort8*>(&Bl[f * LDK2 + k8]) =
            *reinterpret_cast<const ushort8*>(Wt + (size_t)(h * 64 + f) * 128 + k8);
    }
    __syncthreads();
    const int lane = tid & 63, w = tid >> 6;
    const int l15 = lane & 15, lq = lane >> 4;
    f32x4 acc[4] = {};
    for (int ks = 0; ks < 4; ++ks) {
        int koff = ks * 32 + lq * 8;
        bf16x8 af = *reinterpret_cast<const bf16x8*>(&Al[(w * 16 + l15) * LDK2 + koff]);
#pragma unroll
        for (int n = 0; n < 4; ++n) {
            bf16x8 bf_ = *reinterpret_cast<const bf16x8*>(&Bl[(n * 16 + l15) * LDK2 + koff]);
            acc[n] = __builtin_amdgcn_mfma_f32_16x16x32_bf16(af, bf_, acc[n], 0, 0, 0);
        }
    }
    for (int n = 0; n < 4; ++n) {
        int col = h * 64 + n * 16 + l15;
        int rbase = r0 + w * 16 + lq * 4;
#pragma unroll
        for (int r2 = 0; r2 < 4; ++r2) {
            int rr = rbase + r2;
            if (rr < N_NODES) out[(size_t)rr * 512 + col] = acc[n][r2];
        }
    }
}

extern "C" void kernel_launch(void* const* d_in, const int* in_sizes, int n_in,
                              void* d_out, int out_size, void* d_ws, size_t ws_size,
                              hipStream_t stream) {
    const float* x = (const float*)d_in[0];
    const int* edges = (const int*)d_in[1];
    const float* W = (const float*)d_in[2];
    const float* a = (const float*)d_in[3];
    float* out = (float*)d_out;
    const int* src = edges;
    const int* tgt = edges + N_EDGES;

    char* ws = (char*)d_ws;
    size_t off = 0;
    auto alloc = [&](size_t bytes) -> void* {
        void* p = (void*)(ws + off);
        off += (bytes + 255) & ~(size_t)255;
        return p;
    };
    unsigned short* Wt = (unsigned short*)alloc((size_t)HEADS * OUT_F * IN_F * 2);
    float* u = (float*)alloc(HEADS * IN_F * 4);
    float* v = (float*)alloc(HEADS * IN_F * 4);
    unsigned short* xb = (unsigned short*)alloc((size_t)N_NODES * IN_F * 2);  // 25.6 MB
    float* asrc = (float*)alloc((size_t)N_NODES * 8 * 4);
    float* atgt = (float*)alloc((size_t)N_NODES * 8 * 4);
    int* bhist = (int*)alloc((size_t)NBUCK * 4);
    int* bstart = (int*)alloc((size_t)(NBUCK + 1) * 4);
    int* bcursor = (int*)alloc((size_t)NBUCK * 4);
    int* rowptr = (int*)alloc((size_t)(N_NODES + 1) * 4);
    unsigned int* pairs = (unsigned int*)alloc((size_t)N_EDGES * 4);  // 12.8 MB
    int* stgt = (int*)alloc((size_t)N_EDGES * 4);                     // 12.8 MB
    (void)ws_size; (void)n_in; (void)in_sizes; (void)out_size;

    k_prep<<<258, 256, 0, stream>>>(W, a, Wt, u, v, bhist);
    k_xadot<<<25000, 256, 0, stream>>>(x, u, v, xb, asrc, atgt);
    k_bcount<<<NPBLK, 256, 0, stream>>>(src, bhist);
    k_bscan<<<1, 1024, 0, stream>>>(bhist, bstart, bcursor, rowptr);
    k_bscatter<<<NPBLK, 256, 0, stream>>>(src, tgt, bcursor, pairs);
    k_bsort<<<NBUCK, 256, 0, stream>>>(pairs, bstart, rowptr, stgt);
    k_agg9<<<25000, 256, 0, stream>>>(rowptr, stgt, asrc, atgt, xb,
                                      (unsigned short*)d_out);
    k_gemm2<<<dim3(1563, 8), 256, 0, stream>>>((const unsigned short*)d_out, Wt, out);
}

// Round 14
// 505.804 us; speedup vs baseline: 10.2012x; 1.3256x over previous
//
#include <hip/hip_runtime.h>
#include <hip/hip_bf16.h>

#define N_NODES 100000
#define N_EDGES 3200000
#define IN_F 128
#define OUT_F 64
#define HEADS 8
#define ALPHA 0.2f

#define BSHIFT 7
#define NBUCK 782           // ceil(100000 / 128)
#define CHUNK 16384         // edges per partition block
#define NPBLK 196           // ceil(N_EDGES / CHUNK)

typedef __bf16 bf16x8 __attribute__((ext_vector_type(8)));
typedef float f32x4 __attribute__((ext_vector_type(4)));
typedef __attribute__((ext_vector_type(8))) unsigned short ushort8;

static __device__ __forceinline__ unsigned short f2b(float f) {
    __hip_bfloat16 h = __float2bfloat16(f);
    return __builtin_bit_cast(unsigned short, h);
}

static __device__ __forceinline__ void gll16(const void* g, void* l) {
    __builtin_amdgcn_global_load_lds(
        (const __attribute__((address_space(1))) void*)g,
        (__attribute__((address_space(3))) void*)l, 16, 0, 0);
}

// ------- merged prep: Wt transpose (blocks 0-255), u/v (block 256),
//         bhist zero (block 257) ------------------------------------------
__global__ __launch_bounds__(256) void k_prep(const float* __restrict__ W,
                                              const float* __restrict__ a,
                                              unsigned short* __restrict__ Wt,
                                              float* __restrict__ u,
                                              float* __restrict__ v,
                                              int* __restrict__ bhist) {
    int b = blockIdx.x, t = threadIdx.x;
    if (b < 256) {
        int idx = b * 256 + t;          // c*128 + k
        int k = idx & 127;
        int c = idx >> 7;
        int h = c >> 6;
        int f = c & 63;
        Wt[idx] = f2b(W[h * IN_F * OUT_F + k * OUT_F + f]);
    } else if (b == 256) {
#pragma unroll
        for (int j = 0; j < 4; ++j) {
            int t2 = t + j * 256;       // 0..1023 = h*128+k
            int h = t2 >> 7, k = t2 & 127;
            const float* Wrow = W + h * IN_F * OUT_F + k * OUT_F;
            const float* ah = a + h * 2 * OUT_F;
            float su = 0.f, sv = 0.f;
            for (int f = 0; f < OUT_F; ++f) {
                float wv = Wrow[f];
                su += wv * ah[f];
                sv += wv * ah[OUT_F + f];
            }
            u[t2] = su;
            v[t2] = sv;
        }
    } else {
        for (int i = t; i < NBUCK; i += 256) bhist[i] = 0;
    }
}

// ------- fused: x -> bf16 copy, and logits asrc/atgt via u,v dots ----------
__global__ __launch_bounds__(256) void k_xadot(const float* __restrict__ x,
                                               const float* __restrict__ u,
                                               const float* __restrict__ v,
                                               unsigned short* __restrict__ xb,
                                               float* __restrict__ asrc,
                                               float* __restrict__ atgt) {
    int node = (blockIdx.x * 256 + threadIdx.x) >> 6;
    int lane = threadIdx.x & 63;
    if (node >= N_NODES) return;
    float2 xv = *reinterpret_cast<const float2*>(x + (size_t)node * 128 + 2 * lane);
    ushort2 pv = make_ushort2(f2b(xv.x), f2b(xv.y));
    *reinterpret_cast<ushort2*>(xb + (size_t)node * 128 + 2 * lane) = pv;
    for (int h = 0; h < 8; ++h) {
        float2 uu = *reinterpret_cast<const float2*>(u + h * 128 + 2 * lane);
        float2 vv = *reinterpret_cast<const float2*>(v + h * 128 + 2 * lane);
        float s1 = xv.x * uu.x + xv.y * uu.y;
        float s2 = xv.x * vv.x + xv.y * vv.y;
        for (int d = 1; d < 64; d <<= 1) {
            s1 += __shfl_xor(s1, d);
            s2 += __shfl_xor(s2, d);
        }
        if (lane == 0) {
            asrc[node * 8 + h] = s1;
            atgt[node * 8 + h] = s2;
        }
    }
}

// ---------------- pass 0: global bucket histogram (LDS-privatized) --------
__global__ __launch_bounds__(256) void k_bcount(const int* __restrict__ src,
                                                int* __restrict__ bhist) {
    __shared__ int h[NBUCK];
    for (int i = threadIdx.x; i < NBUCK; i += 256) h[i] = 0;
    __syncthreads();
    int i0 = blockIdx.x * CHUNK;
    int iend = i0 + CHUNK;
    if (iend > N_EDGES) iend = N_EDGES;
    for (int i = i0 + threadIdx.x; i < iend; i += 256)
        atomicAdd(&h[src[i] >> BSHIFT], 1);
    __syncthreads();
    for (int i = threadIdx.x; i < NBUCK; i += 256)
        if (h[i]) atomicAdd(&bhist[i], h[i]);
}

// ---------------- bucket scan (1 block); also init cursors ----------------
__global__ __launch_bounds__(1024) void k_bscan(const int* __restrict__ bhist,
                                                int* __restrict__ bstart,
                                                int* __restrict__ bcursor,
                                                int* __restrict__ rowptr) {
    __shared__ int s[1024];
    int t = threadIdx.x;
    int v = (t < NBUCK) ? bhist[t] : 0;
    s[t] = v;
    __syncthreads();
    for (int d = 1; d < 1024; d <<= 1) {
        int add = (t >= d) ? s[t - d] : 0;
        __syncthreads();
        s[t] += add;
        __syncthreads();
    }
    if (t < NBUCK) {
        int st = s[t] - v;
        bstart[t] = st;
        bcursor[t] = st;
    }
    if (t == 0) {
        bstart[NBUCK] = N_EDGES;
        rowptr[N_NODES] = N_EDGES;
    }
}

// ---------------- pass 1: partition edges into bucket regions -------------
// packed pair: (src&127) << 17 | tgt   (tgt < 2^17)
__global__ __launch_bounds__(256) void k_bscatter(const int* __restrict__ src,
                                                  const int* __restrict__ tgt,
                                                  int* __restrict__ bcursor,
                                                  unsigned int* __restrict__ pairs) {
    __shared__ int h[NBUCK];
    __shared__ int rsv[NBUCK];
    for (int i = threadIdx.x; i < NBUCK; i += 256) h[i] = 0;
    __syncthreads();
    int i0 = blockIdx.x * CHUNK;
    int iend = i0 + CHUNK;
    if (iend > N_EDGES) iend = N_EDGES;
    for (int i = i0 + threadIdx.x; i < iend; i += 256)
        atomicAdd(&h[src[i] >> BSHIFT], 1);
    __syncthreads();
    for (int i = threadIdx.x; i < NBUCK; i += 256) {
        int c = h[i];
        rsv[i] = c ? atomicAdd(&bcursor[i], c) : 0;
        h[i] = 0;
    }
    __syncthreads();
    for (int i = i0 + threadIdx.x; i < iend; i += 256) {
        int s = src[i];
        int b = s >> BSHIFT;
        int p = rsv[b] + atomicAdd(&h[b], 1);
        pairs[p] = ((unsigned)(s & 127) << 17) | (unsigned)tgt[i];
    }
}

// ---------------- pass 2: in-bucket counting sort -> stgt + rowptr --------
__global__ __launch_bounds__(256) void k_bsort(const unsigned int* __restrict__ pairs,
                                               const int* __restrict__ bstart,
                                               int* __restrict__ rowptr,
                                               int* __restrict__ stgt) {
    __shared__ int h[128];
    __shared__ int s[128];
    int b = blockIdx.x;
    int p0 = bstart[b], p1 = bstart[b + 1];
    int n0 = b << BSHIFT;
    int t = threadIdx.x;
    if (t < 128) h[t] = 0;
    __syncthreads();
    for (int i = p0 + t; i < p1; i += 256)
        atomicAdd(&h[pairs[i] >> 17], 1);
    __syncthreads();
    int v = (t < 128) ? h[t] : 0;
    if (t < 128) s[t] = v;
    __syncthreads();
    for (int d = 1; d < 128; d <<= 1) {
        int add = (t >= d && t < 128) ? s[t - d] : 0;
        __syncthreads();
        if (t < 128) s[t] += add;
        __syncthreads();
    }
    if (t < 128) {
        int pos = p0 + s[t] - v;
        int node = n0 + t;
        if (node < N_NODES) rowptr[node] = pos;
        h[t] = pos;
    }
    __syncthreads();
    for (int i = p0 + t; i < p1; i += 256) {
        unsigned int pr = pairs[i];
        int pos = atomicAdd(&h[pr >> 17], 1);
        stgt[pos] = (int)(pr & 0x1FFFF);
    }
}

// ------- k_agg6 (round-9 exact): chunk-hoisted weights + pk-FMA ------------
// One wave per node. Chunk = 16 edges. Per-wave LDS buf (x2 dbuf, 5120B):
//   [0..1023]   : atgt rows (32B/edge) -> overwritten in-place with weights
//   [1024..5119]: X[e][seg] 16 edges x 256B bf16 rows
// Weight phase (once/chunk): lane (e=lane&15, hp=lane>>4) computes the two
// weights for its (edge, head-pair) in place; den accumulates per-lane.
// Compute phase: lane (seg=lane&15, hp=lane>>4); per edge 1 ds_read_b128 +
// 1 broadcast ds_read_b64 + 8 unpack + 8 v_pk_fma_f32.
__global__ __launch_bounds__(256) void k_agg6(const int* __restrict__ rowptr,
                                              const int* __restrict__ stgt,
                                              const float* __restrict__ asrc,
                                              const float* __restrict__ atgt,
                                              const unsigned short* __restrict__ xb,
                                              unsigned short* __restrict__ aggout) {
    __shared__ char lds[4 * 2 * 5120];
    const int tid = threadIdx.x;
    const int wid = tid >> 6, lane = tid & 63;
    const int node = blockIdx.x * 4 + wid;
    if (node >= N_NODES) return;
    const int seg = lane & 15;
    const int hp = lane >> 4;
    const int base = rowptr[node], end = rowptr[node + 1];
    const float2 asr = *reinterpret_cast<const float2*>(asrc + (size_t)node * 8 + hp * 2);
    char* wbase = lds + wid * 10240;

    float2 accA[4] = {}, accB[4] = {};
    float den0 = 0.f, den1 = 0.f;

    const int deg = end - base;
    const int nch = (deg + 15) >> 4;

    auto stage = [&](char* buf, int t16) {
        int te_a = __shfl(t16, (lane & 31) >> 1);
        gll16(atgt + (size_t)te_a * 8 + (lane & 1) * 4, buf);
#pragma unroll
        for (int p = 0; p < 4; ++p) {
            int te = __shfl(t16, p * 4 + hp);
            gll16(xb + (size_t)te * 128 + seg * 8, buf + 1024 + p * 1024);
        }
    };

#define EDGE_STEP(E) { \
        uint4 xu = *reinterpret_cast<const uint4*>(Xb + (E) * 256 + seg * 16); \
        float2 w2 = *reinterpret_cast<const float2*>(buf + (E) * 32 + hp * 8); \
        float2 wA = {w2.x, w2.x}, wB = {w2.y, w2.y}; \
        _Pragma("unroll") \
        for (int i = 0; i < 4; ++i) { \
            unsigned int u = (&xu.x)[i]; \
            float2 xv; \
            xv.x = __builtin_bit_cast(float, u << 16); \
            xv.y = __builtin_bit_cast(float, u & 0xFFFF0000u); \
            asm("v_pk_fma_f32 %0, %1, %2, %0" : "+v"(accA[i]) : "v"(xv), "v"(wA)); \
            asm("v_pk_fma_f32 %0, %1, %2, %0" : "+v"(accB[i]) : "v"(xv), "v"(wB)); \
        } }

    if (nch > 0) {
        int i0 = base + seg;
        if (i0 >= end) i0 = end - 1;
        int t16 = stgt[i0];
        stage(wbase, t16);
        if (nch > 1) {
            int i1 = base + 16 + seg;
            if (i1 >= end) i1 = end - 1;
            t16 = stgt[i1];
        }
        asm volatile("s_waitcnt vmcnt(0)" ::: "memory");
        int cur = 0;
        for (int c = 0; c < nch; ++c) {
            if (c + 1 < nch) {
                stage(wbase + (cur ^ 1) * 5120, t16);
                if (c + 2 < nch) {
                    int i2 = base + (c + 2) * 16 + seg;
                    if (i2 >= end) i2 = end - 1;
                    t16 = stgt[i2];
                }
            }
            char* buf = wbase + cur * 5120;
            int c0 = base + c * 16;
            int cnt = end - c0;
            if (cnt > 16) cnt = 16;
            // ---- weight phase: lane (e=seg, hp=q) in-place over buf[0..511]
            {
                float2 at2 = *reinterpret_cast<const float2*>(buf + seg * 32 + hp * 8);
                float z0 = asr.x + at2.x, z1 = asr.y + at2.y;
                float e0 = (z0 > 0.f) ? -z0 : -(ALPHA * z0);
                float e1 = (z1 > 0.f) ? -z1 : -(ALPHA * z1);
                bool ok = seg < cnt;
                float w0 = ok ? __expf(e0) : 0.f;
                float w1 = ok ? __expf(e1) : 0.f;
                den0 += w0;
                den1 += w1;
                float2 wout = {w0, w1};
                *reinterpret_cast<float2*>(buf + seg * 32 + hp * 8) = wout;
            }
            asm volatile("s_waitcnt lgkmcnt(0)" ::: "memory");
            __builtin_amdgcn_sched_barrier(0);
            // ---- compute phase
            const char* Xb = buf + 1024;
            if (cnt == 16) {
#pragma unroll 4
                for (int e = 0; e < 16; ++e) EDGE_STEP(e)
            } else {
                for (int e = 0; e < cnt; ++e) EDGE_STEP(e)
            }
            asm volatile("s_waitcnt vmcnt(0)" ::: "memory");
            cur ^= 1;
        }
    }
#undef EDGE_STEP

    // ---- den: sum over the 16 edge-slots (lanes sharing hp)
    for (int d = 1; d <= 8; d <<= 1) {
        den0 += __shfl_xor(den0, d);
        den1 += __shfl_xor(den1, d);
    }
    float invA = 1.f / (den0 + 1e-10f);
    float invB = 1.f / (den1 + 1e-10f);
    ushort8 oA, oB;
#pragma unroll
    for (int i = 0; i < 4; ++i) {
        oA[2 * i] = f2b(accA[i].x * invA);
        oA[2 * i + 1] = f2b(accA[i].y * invA);
        oB[2 * i] = f2b(accB[i].x * invB);
        oB[2 * i + 1] = f2b(accB[i].y * invB);
    }
    unsigned short* op = aggout + (size_t)node * 1024 + (hp * 2) * 128 + seg * 8;
    *reinterpret_cast<ushort8*>(op) = oA;
    *reinterpret_cast<ushort8*>(op + 128) = oB;
}

// ------- final per-head GEMM: out[r][h*64+f] = agg[r][h][:] @ W[h][:][f] ---
#define LDK2 136
__global__ __launch_bounds__(256) void k_gemm2(const unsigned short* __restrict__ agg,
                                               const unsigned short* __restrict__ Wt,
                                               float* __restrict__ out) {
    __shared__ unsigned short Al[64 * LDK2];
    __shared__ unsigned short Bl[64 * LDK2];
    const int tid = threadIdx.x;
    const int h = blockIdx.y;
    const int r0 = blockIdx.x * 64;
    for (int it = 0; it < 4; ++it) {
        int idx = tid + it * 256;
        int r = idx >> 4, k8 = (idx & 15) << 3;
        int gr = r0 + r;
        if (gr >= N_NODES) gr = N_NODES - 1;
        *reinterpret_cast<ushort8*>(&Al[r * LDK2 + k8]) =
            *reinterpret_cast<const ushort8*>(agg + (size_t)gr * 1024 + h * 128 + k8);
    }
    for (int it = 0; it < 4; ++it) {
        int idx = tid + it * 256;
        int f = idx >> 4, k8 = (idx & 15) << 3;
        *reinterpret_cast<ushort8*>(&Bl[f * LDK2 + k8]) =
            *reinterpret_cast<const ushort8*>(Wt + (size_t)(h * 64 + f) * 128 + k8);
    }
    __syncthreads();
    const int lane = tid & 63, w = tid >> 6;
    const int l15 = lane & 15, lq = lane >> 4;
    f32x4 acc[4] = {};
    for (int ks = 0; ks < 4; ++ks) {
        int koff = ks * 32 + lq * 8;
        bf16x8 af = *reinterpret_cast<const bf16x8*>(&Al[(w * 16 + l15) * LDK2 + koff]);
#pragma unroll
        for (int n = 0; n < 4; ++n) {
            bf16x8 bf_ = *reinterpret_cast<const bf16x8*>(&Bl[(n * 16 + l15) * LDK2 + koff]);
            acc[n] = __builtin_amdgcn_mfma_f32_16x16x32_bf16(af, bf_, acc[n], 0, 0, 0);
        }
    }
    for (int n = 0; n < 4; ++n) {
        int col = h * 64 + n * 16 + l15;
        int rbase = r0 + w * 16 + lq * 4;
#pragma unroll
        for (int r2 = 0; r2 < 4; ++r2) {
            int rr = rbase + r2;
            if (rr < N_NODES) out[(size_t)rr * 512 + col] = acc[n][r2];
        }
    }
}

extern "C" void kernel_launch(void* const* d_in, const int* in_sizes, int n_in,
                              void* d_out, int out_size, void* d_ws, size_t ws_size,
                              hipStream_t stream) {
    const float* x = (const float*)d_in[0];
    const int* edges = (const int*)d_in[1];
    const float* W = (const float*)d_in[2];
    const float* a = (const float*)d_in[3];
    float* out = (float*)d_out;
    const int* src = edges;
    const int* tgt = edges + N_EDGES;

    char* ws = (char*)d_ws;
    size_t off = 0;
    auto alloc = [&](size_t bytes) -> void* {
        void* p = (void*)(ws + off);
        off += (bytes + 255) & ~(size_t)255;
        return p;
    };
    unsigned short* Wt = (unsigned short*)alloc((size_t)HEADS * OUT_F * IN_F * 2);
    float* u = (float*)alloc(HEADS * IN_F * 4);
    float* v = (float*)alloc(HEADS * IN_F * 4);
    unsigned short* xb = (unsigned short*)alloc((size_t)N_NODES * IN_F * 2);  // 25.6 MB
    float* asrc = (float*)alloc((size_t)N_NODES * 8 * 4);
    float* atgt = (float*)alloc((size_t)N_NODES * 8 * 4);
    int* bhist = (int*)alloc((size_t)NBUCK * 4);
    int* bstart = (int*)alloc((size_t)(NBUCK + 1) * 4);
    int* bcursor = (int*)alloc((size_t)NBUCK * 4);
    int* rowptr = (int*)alloc((size_t)(N_NODES + 1) * 4);
    unsigned int* pairs = (unsigned int*)alloc((size_t)N_EDGES * 4);  // 12.8 MB
    int* stgt = (int*)alloc((size_t)N_EDGES * 4);                     // 12.8 MB
    (void)ws_size; (void)n_in; (void)in_sizes; (void)out_size;

    k_prep<<<258, 256, 0, stream>>>(W, a, Wt, u, v, bhist);
    k_xadot<<<25000, 256, 0, stream>>>(x, u, v, xb, asrc, atgt);
    k_bcount<<<NPBLK, 256, 0, stream>>>(src, bhist);
    k_bscan<<<1, 1024, 0, stream>>>(bhist, bstart, bcursor, rowptr);
    k_bscatter<<<NPBLK, 256, 0, stream>>>(src, tgt, bcursor, pairs);
    k_bsort<<<NBUCK, 256, 0, stream>>>(pairs, bstart, rowptr, stgt);
    k_agg6<<<25000, 256, 0, stream>>>(rowptr, stgt, asrc, atgt, xb,
                                      (unsigned short*)d_out);
    k_gemm2<<<dim3(1563, 8), 256, 0, stream>>>((const unsigned short*)d_out, Wt, out);
}

// Round 15
// 492.125 us; speedup vs baseline: 10.4847x; 1.0278x over previous
//
#include <hip/hip_runtime.h>
#include <hip/hip_bf16.h>

#define N_NODES 100000
#define N_EDGES 3200000
#define IN_F 128
#define OUT_F 64
#define HEADS 8
#define ALPHA 0.2f

#define BSHIFT 7
#define NBUCK 782           // ceil(100000 / 128)
#define CHUNK 16384         // edges per partition block
#define NPBLK 196           // ceil(N_EDGES / CHUNK)

typedef __bf16 bf16x8 __attribute__((ext_vector_type(8)));
typedef float f32x4 __attribute__((ext_vector_type(4)));
typedef __attribute__((ext_vector_type(8))) unsigned short ushort8;

static __device__ __forceinline__ unsigned short f2b(float f) {
    __hip_bfloat16 h = __float2bfloat16(f);
    return __builtin_bit_cast(unsigned short, h);
}

static __device__ __forceinline__ void gll16(const void* g, void* l) {
    __builtin_amdgcn_global_load_lds(
        (const __attribute__((address_space(1))) void*)g,
        (__attribute__((address_space(3))) void*)l, 16, 0, 0);
}

// ------- merged prep: Wt transpose (blocks 0-255), u/v (block 256),
//         bhist zero (block 257) ------------------------------------------
__global__ __launch_bounds__(256) void k_prep(const float* __restrict__ W,
                                              const float* __restrict__ a,
                                              unsigned short* __restrict__ Wt,
                                              float* __restrict__ u,
                                              float* __restrict__ v,
                                              int* __restrict__ bhist) {
    int b = blockIdx.x, t = threadIdx.x;
    if (b < 256) {
        int idx = b * 256 + t;          // c*128 + k
        int k = idx & 127;
        int c = idx >> 7;
        int h = c >> 6;
        int f = c & 63;
        Wt[idx] = f2b(W[h * IN_F * OUT_F + k * OUT_F + f]);
    } else if (b == 256) {
#pragma unroll
        for (int j = 0; j < 4; ++j) {
            int t2 = t + j * 256;       // 0..1023 = h*128+k
            int h = t2 >> 7, k = t2 & 127;
            const float* Wrow = W + h * IN_F * OUT_F + k * OUT_F;
            const float* ah = a + h * 2 * OUT_F;
            float su = 0.f, sv = 0.f;
            for (int f = 0; f < OUT_F; ++f) {
                float wv = Wrow[f];
                su += wv * ah[f];
                sv += wv * ah[OUT_F + f];
            }
            u[t2] = su;
            v[t2] = sv;
        }
    } else {
        for (int i = t; i < NBUCK; i += 256) bhist[i] = 0;
    }
}

// ------- fused: x -> bf16 copy, and logits asrc/atgt via u,v dots ----------
__global__ __launch_bounds__(256) void k_xadot(const float* __restrict__ x,
                                               const float* __restrict__ u,
                                               const float* __restrict__ v,
                                               unsigned short* __restrict__ xb,
                                               float* __restrict__ asrc,
                                               float* __restrict__ atgt) {
    int node = (blockIdx.x * 256 + threadIdx.x) >> 6;
    int lane = threadIdx.x & 63;
    if (node >= N_NODES) return;
    float2 xv = *reinterpret_cast<const float2*>(x + (size_t)node * 128 + 2 * lane);
    ushort2 pv = make_ushort2(f2b(xv.x), f2b(xv.y));
    *reinterpret_cast<ushort2*>(xb + (size_t)node * 128 + 2 * lane) = pv;
    for (int h = 0; h < 8; ++h) {
        float2 uu = *reinterpret_cast<const float2*>(u + h * 128 + 2 * lane);
        float2 vv = *reinterpret_cast<const float2*>(v + h * 128 + 2 * lane);
        float s1 = xv.x * uu.x + xv.y * uu.y;
        float s2 = xv.x * vv.x + xv.y * vv.y;
        for (int d = 1; d < 64; d <<= 1) {
            s1 += __shfl_xor(s1, d);
            s2 += __shfl_xor(s2, d);
        }
        if (lane == 0) {
            asrc[node * 8 + h] = s1;
            atgt[node * 8 + h] = s2;
        }
    }
}

// ---------------- pass 0: global bucket histogram (LDS-privatized) --------
__global__ __launch_bounds__(256) void k_bcount(const int* __restrict__ src,
                                                int* __restrict__ bhist) {
    __shared__ int h[NBUCK];
    for (int i = threadIdx.x; i < NBUCK; i += 256) h[i] = 0;
    __syncthreads();
    int i0 = blockIdx.x * CHUNK;
    int iend = i0 + CHUNK;
    if (iend > N_EDGES) iend = N_EDGES;
    for (int i = i0 + threadIdx.x; i < iend; i += 256)
        atomicAdd(&h[src[i] >> BSHIFT], 1);
    __syncthreads();
    for (int i = threadIdx.x; i < NBUCK; i += 256)
        if (h[i]) atomicAdd(&bhist[i], h[i]);
}

// ---------------- bucket scan (1 block); also init cursors ----------------
__global__ __launch_bounds__(1024) void k_bscan(const int* __restrict__ bhist,
                                                int* __restrict__ bstart,
                                                int* __restrict__ bcursor,
                                                int* __restrict__ rowptr) {
    __shared__ int s[1024];
    int t = threadIdx.x;
    int v = (t < NBUCK) ? bhist[t] : 0;
    s[t] = v;
    __syncthreads();
    for (int d = 1; d < 1024; d <<= 1) {
        int add = (t >= d) ? s[t - d] : 0;
        __syncthreads();
        s[t] += add;
        __syncthreads();
    }
    if (t < NBUCK) {
        int st = s[t] - v;
        bstart[t] = st;
        bcursor[t] = st;
    }
    if (t == 0) {
        bstart[NBUCK] = N_EDGES;
        rowptr[N_NODES] = N_EDGES;
    }
}

// ---------------- pass 1: partition edges into bucket regions -------------
// packed pair: (src&127) << 17 | tgt   (tgt < 2^17)
__global__ __launch_bounds__(256) void k_bscatter(const int* __restrict__ src,
                                                  const int* __restrict__ tgt,
                                                  int* __restrict__ bcursor,
                                                  unsigned int* __restrict__ pairs) {
    __shared__ int h[NBUCK];
    __shared__ int rsv[NBUCK];
    for (int i = threadIdx.x; i < NBUCK; i += 256) h[i] = 0;
    __syncthreads();
    int i0 = blockIdx.x * CHUNK;
    int iend = i0 + CHUNK;
    if (iend > N_EDGES) iend = N_EDGES;
    for (int i = i0 + threadIdx.x; i < iend; i += 256)
        atomicAdd(&h[src[i] >> BSHIFT], 1);
    __syncthreads();
    for (int i = threadIdx.x; i < NBUCK; i += 256) {
        int c = h[i];
        rsv[i] = c ? atomicAdd(&bcursor[i], c) : 0;
        h[i] = 0;
    }
    __syncthreads();
    for (int i = i0 + threadIdx.x; i < iend; i += 256) {
        int s = src[i];
        int b = s >> BSHIFT;
        int p = rsv[b] + atomicAdd(&h[b], 1);
        pairs[p] = ((unsigned)(s & 127) << 17) | (unsigned)tgt[i];
    }
}

// ---------------- pass 2: in-bucket counting sort -> stgt + rowptr --------
__global__ __launch_bounds__(256) void k_bsort(const unsigned int* __restrict__ pairs,
                                               const int* __restrict__ bstart,
                                               int* __restrict__ rowptr,
                                               int* __restrict__ stgt) {
    __shared__ int h[128];
    __shared__ int s[128];
    int b = blockIdx.x;
    int p0 = bstart[b], p1 = bstart[b + 1];
    int n0 = b << BSHIFT;
    int t = threadIdx.x;
    if (t < 128) h[t] = 0;
    __syncthreads();
    for (int i = p0 + t; i < p1; i += 256)
        atomicAdd(&h[pairs[i] >> 17], 1);
    __syncthreads();
    int v = (t < 128) ? h[t] : 0;
    if (t < 128) s[t] = v;
    __syncthreads();
    for (int d = 1; d < 128; d <<= 1) {
        int add = (t >= d && t < 128) ? s[t - d] : 0;
        __syncthreads();
        if (t < 128) s[t] += add;
        __syncthreads();
    }
    if (t < 128) {
        int pos = p0 + s[t] - v;
        int node = n0 + t;
        if (node < N_NODES) rowptr[node] = pos;
        h[t] = pos;
    }
    __syncthreads();
    for (int i = p0 + t; i < p1; i += 256) {
        unsigned int pr = pairs[i];
        int pos = atomicAdd(&h[pr >> 17], 1);
        stgt[pos] = (int)(pr & 0x1FFFF);
    }
}

// ------- k_agg10: agg6 + single-buffer (2x occupancy) + op_sel pk_fma -----
// One wave per node. Chunk = 16 edges. Per-wave LDS buf (SINGLE, 5120B):
//   [0..1023]   : atgt rows (32B/edge) -> overwritten in-place with weights
//   [1024..5119]: X[e][seg] 16 edges x 256B bf16 rows
// 20KB/block -> 8 blocks/CU = 32 waves (vs dbuf's 16); TLP hides the
// per-chunk vmcnt(0) stall. op_sel on v_pk_fma_f32 broadcasts w2.lo/w2.hi
// directly (kills 4 splat v_movs/edge). Math identical to agg6.
__global__ __launch_bounds__(256) void k_agg10(const int* __restrict__ rowptr,
                                               const int* __restrict__ stgt,
                                               const float* __restrict__ asrc,
                                               const float* __restrict__ atgt,
                                               const unsigned short* __restrict__ xb,
                                               unsigned short* __restrict__ aggout) {
    __shared__ char lds[4 * 5120];
    const int tid = threadIdx.x;
    const int wid = tid >> 6, lane = tid & 63;
    const int node = blockIdx.x * 4 + wid;
    if (node >= N_NODES) return;
    const int seg = lane & 15;
    const int hp = lane >> 4;
    const int base = rowptr[node], end = rowptr[node + 1];
    const float2 asr = *reinterpret_cast<const float2*>(asrc + (size_t)node * 8 + hp * 2);
    char* buf = lds + wid * 5120;

    float2 accA[4] = {}, accB[4] = {};
    float den0 = 0.f, den1 = 0.f;

    const int deg = end - base;
    const int nch = (deg + 15) >> 4;

    auto eidx = [&](int c) {
        int i = base + c * 16 + seg;
        if (i >= end) i = end - 1;
        return i;
    };
    auto stage = [&](int t16) {
        int te_a = __shfl(t16, (lane & 31) >> 1);
        gll16(atgt + (size_t)te_a * 8 + (lane & 1) * 4, buf);
#pragma unroll
        for (int p = 0; p < 4; ++p) {
            int te = __shfl(t16, p * 4 + hp);
            gll16(xb + (size_t)te * 128 + seg * 8, buf + 1024 + p * 1024);
        }
    };

#define EDGE_STEP(E) { \
        uint4 xu = *reinterpret_cast<const uint4*>(Xb + (E) * 256 + seg * 16); \
        float2 w2 = *reinterpret_cast<const float2*>(buf + (E) * 32 + hp * 8); \
        _Pragma("unroll") \
        for (int i = 0; i < 4; ++i) { \
            unsigned int u = (&xu.x)[i]; \
            float2 xv; \
            xv.x = __builtin_bit_cast(float, u << 16); \
            xv.y = __builtin_bit_cast(float, u & 0xFFFF0000u); \
            asm("v_pk_fma_f32 %0, %1, %2, %0 op_sel:[0,0,0] op_sel_hi:[1,0,1]" \
                : "+v"(accA[i]) : "v"(xv), "v"(w2)); \
            asm("v_pk_fma_f32 %0, %1, %2, %0 op_sel:[0,1,0] op_sel_hi:[1,1,1]" \
                : "+v"(accB[i]) : "v"(xv), "v"(w2)); \
        } }

    if (nch > 0) {
        int t16 = stgt[eidx(0)];
        for (int c = 0; c < nch; ++c) {
            // drain prior chunk's LDS reads before gll overwrites the buffer
            asm volatile("s_waitcnt lgkmcnt(0)" ::: "memory");
            __builtin_amdgcn_sched_barrier(0);
            stage(t16);
            if (c + 1 < nch) t16 = stgt[eidx(c + 1)];
            asm volatile("s_waitcnt vmcnt(0)" ::: "memory");
            __builtin_amdgcn_sched_barrier(0);
            int c0 = base + c * 16;
            int cnt = end - c0;
            if (cnt > 16) cnt = 16;
            // ---- weight phase: lane (e=seg, hp) in-place over buf[0..511]
            {
                float2 at2 = *reinterpret_cast<const float2*>(buf + seg * 32 + hp * 8);
                float z0 = asr.x + at2.x, z1 = asr.y + at2.y;
                float e0 = (z0 > 0.f) ? -z0 : -(ALPHA * z0);
                float e1 = (z1 > 0.f) ? -z1 : -(ALPHA * z1);
                bool ok = seg < cnt;
                float w0 = ok ? __expf(e0) : 0.f;
                float w1 = ok ? __expf(e1) : 0.f;
                den0 += w0;
                den1 += w1;
                float2 wout = {w0, w1};
                *reinterpret_cast<float2*>(buf + seg * 32 + hp * 8) = wout;
            }
            asm volatile("s_waitcnt lgkmcnt(0)" ::: "memory");
            __builtin_amdgcn_sched_barrier(0);
            // ---- compute phase
            const char* Xb = buf + 1024;
            if (cnt == 16) {
#pragma unroll 4
                for (int e = 0; e < 16; ++e) EDGE_STEP(e)
            } else {
                for (int e = 0; e < cnt; ++e) EDGE_STEP(e)
            }
        }
    }
#undef EDGE_STEP

    // ---- den: sum over the 16 edge-slots (lanes sharing hp)
    for (int d = 1; d <= 8; d <<= 1) {
        den0 += __shfl_xor(den0, d);
        den1 += __shfl_xor(den1, d);
    }
    float invA = 1.f / (den0 + 1e-10f);
    float invB = 1.f / (den1 + 1e-10f);
    ushort8 oA, oB;
#pragma unroll
    for (int i = 0; i < 4; ++i) {
        oA[2 * i] = f2b(accA[i].x * invA);
        oA[2 * i + 1] = f2b(accA[i].y * invA);
        oB[2 * i] = f2b(accB[i].x * invB);
        oB[2 * i + 1] = f2b(accB[i].y * invB);
    }
    unsigned short* op = aggout + (size_t)node * 1024 + (hp * 2) * 128 + seg * 8;
    *reinterpret_cast<ushort8*>(op) = oA;
    *reinterpret_cast<ushort8*>(op + 128) = oB;
}

// ------- final per-head GEMM: out[r][h*64+f] = agg[r][h][:] @ W[h][:][f] ---
#define LDK2 136
__global__ __launch_bounds__(256) void k_gemm2(const unsigned short* __restrict__ agg,
                                               const unsigned short* __restrict__ Wt,
                                               float* __restrict__ out) {
    __shared__ unsigned short Al[64 * LDK2];
    __shared__ unsigned short Bl[64 * LDK2];
    const int tid = threadIdx.x;
    const int h = blockIdx.y;
    const int r0 = blockIdx.x * 64;
    for (int it = 0; it < 4; ++it) {
        int idx = tid + it * 256;
        int r = idx >> 4, k8 = (idx & 15) << 3;
        int gr = r0 + r;
        if (gr >= N_NODES) gr = N_NODES - 1;
        *reinterpret_cast<ushort8*>(&Al[r * LDK2 + k8]) =
            *reinterpret_cast<const ushort8*>(agg + (size_t)gr * 1024 + h * 128 + k8);
    }
    for (int it = 0; it < 4; ++it) {
        int idx = tid + it * 256;
        int f = idx >> 4, k8 = (idx & 15) << 3;
        *reinterpret_cast<ushort8*>(&Bl[f * LDK2 + k8]) =
            *reinterpret_cast<const ushort8*>(Wt + (size_t)(h * 64 + f) * 128 + k8);
    }
    __syncthreads();
    const int lane = tid & 63, w = tid >> 6;
    const int l15 = lane & 15, lq = lane >> 4;
    f32x4 acc[4] = {};
    for (int ks = 0; ks < 4; ++ks) {
        int koff = ks * 32 + lq * 8;
        bf16x8 af = *reinterpret_cast<const bf16x8*>(&Al[(w * 16 + l15) * LDK2 + koff]);
#pragma unroll
        for (int n = 0; n < 4; ++n) {
            bf16x8 bf_ = *reinterpret_cast<const bf16x8*>(&Bl[(n * 16 + l15) * LDK2 + koff]);
            acc[n] = __builtin_amdgcn_mfma_f32_16x16x32_bf16(af, bf_, acc[n], 0, 0, 0);
        }
    }
    for (int n = 0; n < 4; ++n) {
        int col = h * 64 + n * 16 + l15;
        int rbase = r0 + w * 16 + lq * 4;
#pragma unroll
        for (int r2 = 0; r2 < 4; ++r2) {
            int rr = rbase + r2;
            if (rr < N_NODES) out[(size_t)rr * 512 + col] = acc[n][r2];
        }
    }
}

extern "C" void kernel_launch(void* const* d_in, const int* in_sizes, int n_in,
                              void* d_out, int out_size, void* d_ws, size_t ws_size,
                              hipStream_t stream) {
    const float* x = (const float*)d_in[0];
    const int* edges = (const int*)d_in[1];
    const float* W = (const float*)d_in[2];
    const float* a = (const float*)d_in[3];
    float* out = (float*)d_out;
    const int* src = edges;
    const int* tgt = edges + N_EDGES;

    char* ws = (char*)d_ws;
    size_t off = 0;
    auto alloc = [&](size_t bytes) -> void* {
        void* p = (void*)(ws + off);
        off += (bytes + 255) & ~(size_t)255;
        return p;
    };
    unsigned short* Wt = (unsigned short*)alloc((size_t)HEADS * OUT_F * IN_F * 2);
    float* u = (float*)alloc(HEADS * IN_F * 4);
    float* v = (float*)alloc(HEADS * IN_F * 4);
    unsigned short* xb = (unsigned short*)alloc((size_t)N_NODES * IN_F * 2);  // 25.6 MB
    float* asrc = (float*)alloc((size_t)N_NODES * 8 * 4);
    float* atgt = (float*)alloc((size_t)N_NODES * 8 * 4);
    int* bhist = (int*)alloc((size_t)NBUCK * 4);
    int* bstart = (int*)alloc((size_t)(NBUCK + 1) * 4);
    int* bcursor = (int*)alloc((size_t)NBUCK * 4);
    int* rowptr = (int*)alloc((size_t)(N_NODES + 1) * 4);
    unsigned int* pairs = (unsigned int*)alloc((size_t)N_EDGES * 4);  // 12.8 MB
    int* stgt = (int*)alloc((size_t)N_EDGES * 4);                     // 12.8 MB
    (void)ws_size; (void)n_in; (void)in_sizes; (void)out_size;

    k_prep<<<258, 256, 0, stream>>>(W, a, Wt, u, v, bhist);
    k_xadot<<<25000, 256, 0, stream>>>(x, u, v, xb, asrc, atgt);
    k_bcount<<<NPBLK, 256, 0, stream>>>(src, bhist);
    k_bscan<<<1, 1024, 0, stream>>>(bhist, bstart, bcursor, rowptr);
    k_bscatter<<<NPBLK, 256, 0, stream>>>(src, tgt, bcursor, pairs);
    k_bsort<<<NBUCK, 256, 0, stream>>>(pairs, bstart, rowptr, stgt);
    k_agg10<<<25000, 256, 0, stream>>>(rowptr, stgt, asrc, atgt, xb,
                                       (unsigned short*)d_out);
    k_gemm2<<<dim3(1563, 8), 256, 0, stream>>>((const unsigned short*)d_out, Wt, out);
}

// Round 16
// 453.983 us; speedup vs baseline: 11.3656x; 1.0840x over previous
//
#include <hip/hip_runtime.h>
#include <hip/hip_bf16.h>

#define N_NODES 100000
#define N_EDGES 3200000
#define IN_F 128
#define OUT_F 64
#define HEADS 8
#define ALPHA 0.2f

#define BSHIFT 7
#define NBUCK 782           // ceil(100000 / 128)
#define CHUNK 2048          // edges per partition block (was 16384: 196 blocks
                            // = <1 block/CU -> severe underutilization)
#define NPBLK 1563          // ceil(N_EDGES / CHUNK)
#define XADOT_BLKS 1024     // node-work blocks in the fused xadot+bcount kernel

typedef __bf16 bf16x8 __attribute__((ext_vector_type(8)));
typedef float f32x4 __attribute__((ext_vector_type(4)));
typedef __attribute__((ext_vector_type(8))) unsigned short ushort8;

static __device__ __forceinline__ unsigned short f2b(float f) {
    __hip_bfloat16 h = __float2bfloat16(f);
    return __builtin_bit_cast(unsigned short, h);
}

static __device__ __forceinline__ void gll16(const void* g, void* l) {
    __builtin_amdgcn_global_load_lds(
        (const __attribute__((address_space(1))) void*)g,
        (__attribute__((address_space(3))) void*)l, 16, 0, 0);
}

// ------- merged prep: Wt transpose (blocks 0-255), uvT (block 256),
//         bhist zero (block 257) ------------------------------------------
// uvT[k][c], c<8: u for head c; c>=8: v for head c-8.
__global__ __launch_bounds__(256) void k_prep(const float* __restrict__ W,
                                              const float* __restrict__ a,
                                              unsigned short* __restrict__ Wt,
                                              float* __restrict__ uvT,
                                              int* __restrict__ bhist) {
    int b = blockIdx.x, t = threadIdx.x;
    if (b < 256) {
        int idx = b * 256 + t;          // c*128 + k
        int k = idx & 127;
        int c = idx >> 7;
        int h = c >> 6;
        int f = c & 63;
        Wt[idx] = f2b(W[h * IN_F * OUT_F + k * OUT_F + f]);
    } else if (b == 256) {
#pragma unroll
        for (int j = 0; j < 4; ++j) {
            int t2 = t + j * 256;       // 0..1023 = h*128+k
            int h = t2 >> 7, k = t2 & 127;
            const float* Wrow = W + h * IN_F * OUT_F + k * OUT_F;
            const float* ah = a + h * 2 * OUT_F;
            float su = 0.f, sv = 0.f;
            for (int f = 0; f < OUT_F; ++f) {
                float wv = Wrow[f];
                su += wv * ah[f];
                sv += wv * ah[OUT_F + f];
            }
            uvT[k * 16 + h] = su;
            uvT[k * 16 + 8 + h] = sv;
        }
    } else {
        for (int i = t; i < NBUCK; i += 256) bhist[i] = 0;
    }
}

// ------- fused: xadot (blocks < XADOT_BLKS, grid-stride over nodes) +
//         bucket histogram (blocks >= XADOT_BLKS) --------------------------
// xadot lane (o=lane&15, q=lane>>4): preloads uvT[q*32+j][o] j=0..31 into
// registers; per node: 8 broadcast float4 x-loads + 32 fma + 2 shfl_xor.
__global__ __launch_bounds__(256) void k_xadot(const float* __restrict__ x,
                                               const float* __restrict__ uvT,
                                               const int* __restrict__ src,
                                               unsigned short* __restrict__ xb,
                                               float* __restrict__ asrc,
                                               float* __restrict__ atgt,
                                               int* __restrict__ bhist) {
    const int b = blockIdx.x, t = threadIdx.x;
    if (b >= XADOT_BLKS) {
        // ---- bucket histogram chunk
        __shared__ int h[NBUCK];
        for (int i = t; i < NBUCK; i += 256) h[i] = 0;
        __syncthreads();
        int cb = b - XADOT_BLKS;
        int i0 = cb * CHUNK;
        int iend = i0 + CHUNK;
        if (iend > N_EDGES) iend = N_EDGES;
        for (int i = i0 + t; i < iend; i += 256)
            atomicAdd(&h[src[i] >> BSHIFT], 1);
        __syncthreads();
        for (int i = t; i < NBUCK; i += 256)
            if (h[i]) atomicAdd(&bhist[i], h[i]);
        return;
    }
    const int lane = t & 63, wid = t >> 6;
    const int o = lane & 15, q = lane >> 4;
    // preload this lane's uvT column slice (static unroll -> registers)
    float up[32];
#pragma unroll
    for (int j = 0; j < 32; ++j) up[j] = uvT[(q * 32 + j) * 16 + o];

    for (int n = b * 4 + wid; n < N_NODES; n += XADOT_BLKS * 4) {
        const float* xr = x + (size_t)n * 128;
        // xb bf16 copy (row is L1-hot)
        float2 xv2 = *reinterpret_cast<const float2*>(xr + 2 * lane);
        ushort2 pv = make_ushort2(f2b(xv2.x), f2b(xv2.y));
        *reinterpret_cast<ushort2*>(xb + (size_t)n * 128 + 2 * lane) = pv;
        // dot: partial over this quarter's 32 elems
        float r = 0.f;
        const float4* xq = reinterpret_cast<const float4*>(xr + q * 32);
#pragma unroll
        for (int j = 0; j < 8; ++j) {
            float4 xv = xq[j];
            r = fmaf(xv.x, up[4 * j], r);
            r = fmaf(xv.y, up[4 * j + 1], r);
            r = fmaf(xv.z, up[4 * j + 2], r);
            r = fmaf(xv.w, up[4 * j + 3], r);
        }
        r += __shfl_xor(r, 16);
        r += __shfl_xor(r, 32);
        if (lane < 8) asrc[n * 8 + o] = r;
        else if (lane < 16) atgt[n * 8 + (o - 8)] = r;
    }
}

// ---------------- bucket scan (1 block); also init cursors ----------------
__global__ __launch_bounds__(1024) void k_bscan(const int* __restrict__ bhist,
                                                int* __restrict__ bstart,
                                                int* __restrict__ bcursor,
                                                int* __restrict__ rowptr) {
    __shared__ int s[1024];
    int t = threadIdx.x;
    int v = (t < NBUCK) ? bhist[t] : 0;
    s[t] = v;
    __syncthreads();
    for (int d = 1; d < 1024; d <<= 1) {
        int add = (t >= d) ? s[t - d] : 0;
        __syncthreads();
        s[t] += add;
        __syncthreads();
    }
    if (t < NBUCK) {
        int st = s[t] - v;
        bstart[t] = st;
        bcursor[t] = st;
    }
    if (t == 0) {
        bstart[NBUCK] = N_EDGES;
        rowptr[N_NODES] = N_EDGES;
    }
}

// ---------------- pass 1: partition edges into bucket regions -------------
// packed pair: (src&127) << 17 | tgt   (tgt < 2^17)
__global__ __launch_bounds__(256) void k_bscatter(const int* __restrict__ src,
                                                  const int* __restrict__ tgt,
                                                  int* __restrict__ bcursor,
                                                  unsigned int* __restrict__ pairs) {
    __shared__ int h[NBUCK];
    __shared__ int rsv[NBUCK];
    for (int i = threadIdx.x; i < NBUCK; i += 256) h[i] = 0;
    __syncthreads();
    int i0 = blockIdx.x * CHUNK;
    int iend = i0 + CHUNK;
    if (iend > N_EDGES) iend = N_EDGES;
    for (int i = i0 + threadIdx.x; i < iend; i += 256)
        atomicAdd(&h[src[i] >> BSHIFT], 1);
    __syncthreads();
    for (int i = threadIdx.x; i < NBUCK; i += 256) {
        int c = h[i];
        rsv[i] = c ? atomicAdd(&bcursor[i], c) : 0;
        h[i] = 0;
    }
    __syncthreads();
    for (int i = i0 + threadIdx.x; i < iend; i += 256) {
        int s = src[i];
        int b = s >> BSHIFT;
        int p = rsv[b] + atomicAdd(&h[b], 1);
        pairs[p] = ((unsigned)(s & 127) << 17) | (unsigned)tgt[i];
    }
}

// ---------------- pass 2: in-bucket counting sort -> stgt + rowptr --------
__global__ __launch_bounds__(512) void k_bsort(const unsigned int* __restrict__ pairs,
                                               const int* __restrict__ bstart,
                                               int* __restrict__ rowptr,
                                               int* __restrict__ stgt) {
    __shared__ int h[128];
    __shared__ int s[128];
    int b = blockIdx.x;
    int p0 = bstart[b], p1 = bstart[b + 1];
    int n0 = b << BSHIFT;
    int t = threadIdx.x;
    if (t < 128) h[t] = 0;
    __syncthreads();
    for (int i = p0 + t; i < p1; i += 512)
        atomicAdd(&h[pairs[i] >> 17], 1);
    __syncthreads();
    int v = (t < 128) ? h[t] : 0;
    if (t < 128) s[t] = v;
    __syncthreads();
    for (int d = 1; d < 128; d <<= 1) {
        int add = (t >= d && t < 128) ? s[t - d] : 0;
        __syncthreads();
        if (t < 128) s[t] += add;
        __syncthreads();
    }
    if (t < 128) {
        int pos = p0 + s[t] - v;
        int node = n0 + t;
        if (node < N_NODES) rowptr[node] = pos;
        h[t] = pos;
    }
    __syncthreads();
    for (int i = p0 + t; i < p1; i += 512) {
        unsigned int pr = pairs[i];
        int pos = atomicAdd(&h[pr >> 17], 1);
        stgt[pos] = (int)(pr & 0x1FFFF);
    }
}

// ------- k_agg10: single-buffer, op_sel pk_fma (round-15 exact) -----------
__global__ __launch_bounds__(256) void k_agg10(const int* __restrict__ rowptr,
                                               const int* __restrict__ stgt,
                                               const float* __restrict__ asrc,
                                               const float* __restrict__ atgt,
                                               const unsigned short* __restrict__ xb,
                                               unsigned short* __restrict__ aggout) {
    __shared__ char lds[4 * 5120];
    const int tid = threadIdx.x;
    const int wid = tid >> 6, lane = tid & 63;
    const int node = blockIdx.x * 4 + wid;
    if (node >= N_NODES) return;
    const int seg = lane & 15;
    const int hp = lane >> 4;
    const int base = rowptr[node], end = rowptr[node + 1];
    const float2 asr = *reinterpret_cast<const float2*>(asrc + (size_t)node * 8 + hp * 2);
    char* buf = lds + wid * 5120;

    float2 accA[4] = {}, accB[4] = {};
    float den0 = 0.f, den1 = 0.f;

    const int deg = end - base;
    const int nch = (deg + 15) >> 4;

    auto eidx = [&](int c) {
        int i = base + c * 16 + seg;
        if (i >= end) i = end - 1;
        return i;
    };
    auto stage = [&](int t16) {
        int te_a = __shfl(t16, (lane & 31) >> 1);
        gll16(atgt + (size_t)te_a * 8 + (lane & 1) * 4, buf);
#pragma unroll
        for (int p = 0; p < 4; ++p) {
            int te = __shfl(t16, p * 4 + hp);
            gll16(xb + (size_t)te * 128 + seg * 8, buf + 1024 + p * 1024);
        }
    };

#define EDGE_STEP(E) { \
        uint4 xu = *reinterpret_cast<const uint4*>(Xb + (E) * 256 + seg * 16); \
        float2 w2 = *reinterpret_cast<const float2*>(buf + (E) * 32 + hp * 8); \
        _Pragma("unroll") \
        for (int i = 0; i < 4; ++i) { \
            unsigned int u = (&xu.x)[i]; \
            float2 xv; \
            xv.x = __builtin_bit_cast(float, u << 16); \
            xv.y = __builtin_bit_cast(float, u & 0xFFFF0000u); \
            asm("v_pk_fma_f32 %0, %1, %2, %0 op_sel:[0,0,0] op_sel_hi:[1,0,1]" \
                : "+v"(accA[i]) : "v"(xv), "v"(w2)); \
            asm("v_pk_fma_f32 %0, %1, %2, %0 op_sel:[0,1,0] op_sel_hi:[1,1,1]" \
                : "+v"(accB[i]) : "v"(xv), "v"(w2)); \
        } }

    if (nch > 0) {
        int t16 = stgt[eidx(0)];
        for (int c = 0; c < nch; ++c) {
            asm volatile("s_waitcnt lgkmcnt(0)" ::: "memory");
            __builtin_amdgcn_sched_barrier(0);
            stage(t16);
            if (c + 1 < nch) t16 = stgt[eidx(c + 1)];
            asm volatile("s_waitcnt vmcnt(0)" ::: "memory");
            __builtin_amdgcn_sched_barrier(0);
            int c0 = base + c * 16;
            int cnt = end - c0;
            if (cnt > 16) cnt = 16;
            {
                float2 at2 = *reinterpret_cast<const float2*>(buf + seg * 32 + hp * 8);
                float z0 = asr.x + at2.x, z1 = asr.y + at2.y;
                float e0 = (z0 > 0.f) ? -z0 : -(ALPHA * z0);
                float e1 = (z1 > 0.f) ? -z1 : -(ALPHA * z1);
                bool ok = seg < cnt;
                float w0 = ok ? __expf(e0) : 0.f;
                float w1 = ok ? __expf(e1) : 0.f;
                den0 += w0;
                den1 += w1;
                float2 wout = {w0, w1};
                *reinterpret_cast<float2*>(buf + seg * 32 + hp * 8) = wout;
            }
            asm volatile("s_waitcnt lgkmcnt(0)" ::: "memory");
            __builtin_amdgcn_sched_barrier(0);
            const char* Xb = buf + 1024;
            if (cnt == 16) {
#pragma unroll 4
                for (int e = 0; e < 16; ++e) EDGE_STEP(e)
            } else {
                for (int e = 0; e < cnt; ++e) EDGE_STEP(e)
            }
        }
    }
#undef EDGE_STEP

    for (int d = 1; d <= 8; d <<= 1) {
        den0 += __shfl_xor(den0, d);
        den1 += __shfl_xor(den1, d);
    }
    float invA = 1.f / (den0 + 1e-10f);
    float invB = 1.f / (den1 + 1e-10f);
    ushort8 oA, oB;
#pragma unroll
    for (int i = 0; i < 4; ++i) {
        oA[2 * i] = f2b(accA[i].x * invA);
        oA[2 * i + 1] = f2b(accA[i].y * invA);
        oB[2 * i] = f2b(accB[i].x * invB);
        oB[2 * i + 1] = f2b(accB[i].y * invB);
    }
    unsigned short* op = aggout + (size_t)node * 1024 + (hp * 2) * 128 + seg * 8;
    *reinterpret_cast<ushort8*>(op) = oA;
    *reinterpret_cast<ushort8*>(op + 128) = oB;
}

// ------- final per-head GEMM: out[r][h*64+f] = agg[r][h][:] @ W[h][:][f] ---
#define LDK2 136
__global__ __launch_bounds__(256) void k_gemm2(const unsigned short* __restrict__ agg,
                                               const unsigned short* __restrict__ Wt,
                                               float* __restrict__ out) {
    __shared__ unsigned short Al[64 * LDK2];
    __shared__ unsigned short Bl[64 * LDK2];
    const int tid = threadIdx.x;
    const int h = blockIdx.y;
    const int r0 = blockIdx.x * 64;
    for (int it = 0; it < 4; ++it) {
        int idx = tid + it * 256;
        int r = idx >> 4, k8 = (idx & 15) << 3;
        int gr = r0 + r;
        if (gr >= N_NODES) gr = N_NODES - 1;
        *reinterpret_cast<ushort8*>(&Al[r * LDK2 + k8]) =
            *reinterpret_cast<const ushort8*>(agg + (size_t)gr * 1024 + h * 128 + k8);
    }
    for (int it = 0; it < 4; ++it) {
        int idx = tid + it * 256;
        int f = idx >> 4, k8 = (idx & 15) << 3;
        *reinterpret_cast<ushort8*>(&Bl[f * LDK2 + k8]) =
            *reinterpret_cast<const ushort8*>(Wt + (size_t)(h * 64 + f) * 128 + k8);
    }
    __syncthreads();
    const int lane = tid & 63, w = tid >> 6;
    const int l15 = lane & 15, lq = lane >> 4;
    f32x4 acc[4] = {};
    for (int ks = 0; ks < 4; ++ks) {
        int koff = ks * 32 + lq * 8;
        bf16x8 af = *reinterpret_cast<const bf16x8*>(&Al[(w * 16 + l15) * LDK2 + koff]);
#pragma unroll
        for (int n = 0; n < 4; ++n) {
            bf16x8 bf_ = *reinterpret_cast<const bf16x8*>(&Bl[(n * 16 + l15) * LDK2 + koff]);
            acc[n] = __builtin_amdgcn_mfma_f32_16x16x32_bf16(af, bf_, acc[n], 0, 0, 0);
        }
    }
    for (int n = 0; n < 4; ++n) {
        int col = h * 64 + n * 16 + l15;
        int rbase = r0 + w * 16 + lq * 4;
#pragma unroll
        for (int r2 = 0; r2 < 4; ++r2) {
            int rr = rbase + r2;
            if (rr < N_NODES) out[(size_t)rr * 512 + col] = acc[n][r2];
        }
    }
}

extern "C" void kernel_launch(void* const* d_in, const int* in_sizes, int n_in,
                              void* d_out, int out_size, void* d_ws, size_t ws_size,
                              hipStream_t stream) {
    const float* x = (const float*)d_in[0];
    const int* edges = (const int*)d_in[1];
    const float* W = (const float*)d_in[2];
    const float* a = (const float*)d_in[3];
    float* out = (float*)d_out;
    const int* src = edges;
    const int* tgt = edges + N_EDGES;

    char* ws = (char*)d_ws;
    size_t off = 0;
    auto alloc = [&](size_t bytes) -> void* {
        void* p = (void*)(ws + off);
        off += (bytes + 255) & ~(size_t)255;
        return p;
    };
    unsigned short* Wt = (unsigned short*)alloc((size_t)HEADS * OUT_F * IN_F * 2);
    float* uvT = (float*)alloc((size_t)IN_F * 16 * 4);
    unsigned short* xb = (unsigned short*)alloc((size_t)N_NODES * IN_F * 2);  // 25.6 MB
    float* asrc = (float*)alloc((size_t)N_NODES * 8 * 4);
    float* atgt = (float*)alloc((size_t)N_NODES * 8 * 4);
    int* bhist = (int*)alloc((size_t)NBUCK * 4);
    int* bstart = (int*)alloc((size_t)(NBUCK + 1) * 4);
    int* bcursor = (int*)alloc((size_t)NBUCK * 4);
    int* rowptr = (int*)alloc((size_t)(N_NODES + 1) * 4);
    unsigned int* pairs = (unsigned int*)alloc((size_t)N_EDGES * 4);  // 12.8 MB
    int* stgt = (int*)alloc((size_t)N_EDGES * 4);                     // 12.8 MB
    (void)ws_size; (void)n_in; (void)in_sizes; (void)out_size;

    k_prep<<<258, 256, 0, stream>>>(W, a, Wt, uvT, bhist);
    k_xadot<<<XADOT_BLKS + NPBLK, 256, 0, stream>>>(x, uvT, src, xb, asrc, atgt, bhist);
    k_bscan<<<1, 1024, 0, stream>>>(bhist, bstart, bcursor, rowptr);
    k_bscatter<<<NPBLK, 256, 0, stream>>>(src, tgt, bcursor, pairs);
    k_bsort<<<NBUCK, 512, 0, stream>>>(pairs, bstart, rowptr, stgt);
    k_agg10<<<25000, 256, 0, stream>>>(rowptr, stgt, asrc, atgt, xb,
                                       (unsigned short*)d_out);
    k_gemm2<<<dim3(1563, 8), 256, 0, stream>>>((const unsigned short*)d_out, Wt, out);
}